// Round 1
// baseline (1809.718 us; speedup 1.0000x reference)
//
#include <hip/hip_runtime.h>
#include <hip/hip_bf16.h>

#define EPSBN 1e-3f

// ---------------------------------------------------------------------------
// Layout constants
//   x    : (16, 64, 49, 1024) f32
//   ext0 : (16, 64, 2, 1024)  f32   [s=0: max over 49, s=1: mean]
//   z0   : (16, 32, 51, 1280) f32   reference channel order (pn*8+g)
//   ext1 : (16, 32, 2, 1280)  f32
//   out  : (16, 16, 53, 1600) f32
// ---------------------------------------------------------------------------

__global__ __launch_bounds__(256) void tc_reduce0(const float* __restrict__ x,
                                                  float* __restrict__ ext) {
    const int bt = blockIdx.x;              // 0..1023  (b*64+t)
    const int c  = threadIdx.x * 4;         // 0..1020
    const float4* src = reinterpret_cast<const float4*>(x + (size_t)bt * 49 * 1024 + c);
    float4 v = src[0];
    float mx0 = v.x, mx1 = v.y, mx2 = v.z, mx3 = v.w;
    float sm0 = v.x, sm1 = v.y, sm2 = v.z, sm3 = v.w;
    for (int s = 1; s < 49; ++s) {
        float4 u = src[(size_t)s * 256];
        mx0 = fmaxf(mx0, u.x); sm0 += u.x;
        mx1 = fmaxf(mx1, u.y); sm1 += u.y;
        mx2 = fmaxf(mx2, u.z); sm2 += u.z;
        mx3 = fmaxf(mx3, u.w); sm3 += u.w;
    }
    const float inv = 1.0f / 49.0f;
    float* dmax  = ext + (size_t)bt * 2048 + c;
    *reinterpret_cast<float4*>(dmax)        = make_float4(mx0, mx1, mx2, mx3);
    *reinterpret_cast<float4*>(dmax + 1024) = make_float4(sm0*inv, sm1*inv, sm2*inv, sm3*inv);
}

__global__ __launch_bounds__(320) void tc_reduce1(const float* __restrict__ z,
                                                  float* __restrict__ ext) {
    const int bt = blockIdx.x;              // 0..511  (b*32+t)
    const int c  = threadIdx.x * 4;         // 0..1276
    const float4* src = reinterpret_cast<const float4*>(z + (size_t)bt * 51 * 1280 + c);
    float4 v = src[0];
    float mx0 = v.x, mx1 = v.y, mx2 = v.z, mx3 = v.w;
    float sm0 = v.x, sm1 = v.y, sm2 = v.z, sm3 = v.w;
    for (int s = 1; s < 51; ++s) {
        float4 u = src[(size_t)s * 320];    // 1280 floats = 320 float4
        mx0 = fmaxf(mx0, u.x); sm0 += u.x;
        mx1 = fmaxf(mx1, u.y); sm1 += u.y;
        mx2 = fmaxf(mx2, u.z); sm2 += u.z;
        mx3 = fmaxf(mx3, u.w); sm3 += u.w;
    }
    const float inv = 1.0f / 51.0f;
    float* dmax  = ext + (size_t)bt * 2560 + c;
    *reinterpret_cast<float4*>(dmax)        = make_float4(mx0, mx1, mx2, mx3);
    *reinterpret_cast<float4*>(dmax + 1280) = make_float4(sm0*inv, sm1*inv, sm2*inv, sm3*inv);
}

// ---------------------------------------------------------------------------
// Layer 0: per-block (b, s<51, g<8).  A = x column (64 x 128), W = (128 x 160),
// Y = A*W + bias (64 x 160) kept in LDS, then temporal ops -> z0.
// ---------------------------------------------------------------------------
__global__ __launch_bounds__(256) void tc_layer0(
    const float* __restrict__ x, const float* __restrict__ ext,
    const float* __restrict__ w, const float* __restrict__ bias,
    const float* __restrict__ k3, const float* __restrict__ k5,
    const float* __restrict__ k7,
    const float* __restrict__ gam, const float* __restrict__ bet,
    const float* __restrict__ mu, const float* __restrict__ var,
    float* __restrict__ z)
{
    const int tid = threadIdx.x;
    const int g  = blockIdx.x & 7;
    const int bs = blockIdx.x >> 3;
    const int s  = bs % 51;
    const int b  = bs / 51;

    __shared__ float lds[64*132 + 32*160];      // 13568 floats = 54.3 KB
    float* Alds = lds;                          // 64 x 128, stride 132
    float* Blds = lds + 64*132;                 // 32 x 160
    float* Ylds = lds;                          // 64 x 160, stride 164 (overlaps after GEMM)

    // ---- load A (64 t x 128 k) ----
    #pragma unroll
    for (int it = 0; it < 8; ++it) {
        const int fid = tid + it*256;           // < 2048
        const int t  = fid >> 5;
        const int k4 = (fid & 31) * 4;
        const float* src = (s < 49)
            ? x   + ((size_t)(b*64 + t)*49 + s) * 1024 + g*128 + k4
            : ext + ((size_t)(b*64 + t)*2 + (s-49)) * 1024 + g*128 + k4;
        *reinterpret_cast<float4*>(&Alds[t*132 + k4]) = *reinterpret_cast<const float4*>(src);
    }

    const int ry = tid >> 4;                    // 0..15 -> rows ry*4+i
    const int cx = tid & 15;                    // 0..15 -> cols cx*10+j
    float acc[4][10];
    #pragma unroll
    for (int i = 0; i < 4; ++i)
        #pragma unroll
        for (int j = 0; j < 10; ++j) acc[i][j] = 0.f;

    for (int k0 = 0; k0 < 128; k0 += 32) {
        __syncthreads();
        #pragma unroll
        for (int it = 0; it < 20; ++it) {       // stage 32 x 160 W-chunk
            const int fid = tid + it*256;       // < 5120
            const int kk = fid / 160;
            const int pn = fid - kk*160;
            const int p = pn >> 5, n = pn & 31;
            Blds[kk*160 + pn] = w[(((size_t)p*8 + g)*128 + (k0+kk))*32 + n];
        }
        __syncthreads();
        #pragma unroll 8
        for (int kk = 0; kk < 32; ++kk) {
            const float a0 = Alds[(ry*4+0)*132 + k0+kk];
            const float a1 = Alds[(ry*4+1)*132 + k0+kk];
            const float a2 = Alds[(ry*4+2)*132 + k0+kk];
            const float a3 = Alds[(ry*4+3)*132 + k0+kk];
            const float2* br = reinterpret_cast<const float2*>(&Blds[kk*160 + cx*10]);
            const float2 q0 = br[0], q1 = br[1], q2 = br[2], q3 = br[3], q4 = br[4];
            const float bb[10] = {q0.x,q0.y,q1.x,q1.y,q2.x,q2.y,q3.x,q3.y,q4.x,q4.y};
            #pragma unroll
            for (int j = 0; j < 10; ++j) {
                acc[0][j] = fmaf(a0, bb[j], acc[0][j]);
                acc[1][j] = fmaf(a1, bb[j], acc[1][j]);
                acc[2][j] = fmaf(a2, bb[j], acc[2][j]);
                acc[3][j] = fmaf(a3, bb[j], acc[3][j]);
            }
        }
    }
    __syncthreads();

    // ---- bias + stash Y ----
    #pragma unroll
    for (int i = 0; i < 4; ++i) {
        const int row = ry*4 + i;
        #pragma unroll
        for (int j = 0; j < 10; ++j) {
            const int pn = cx*10 + j;
            const int p = pn >> 5, n = pn & 31;
            Ylds[row*164 + pn] = acc[i][j] + bias[(p*8 + g)*32 + n];
        }
    }
    __syncthreads();

    // ---- temporal branch + BN + relu + shuffle + T-pool(2) ----
    for (int oi = 0; oi < 20; ++oi) {
        const int idx = tid + oi*256;           // < 5120 = 32*160
        const int tq = idx / 160;
        const int pn = idx - tq*160;
        const int p = pn >> 5, n = pn & 31;
        float vv[2];
        #pragma unroll
        for (int q = 0; q < 2; ++q) {
            const int t = 2*tq + q;
            float v;
            if (p == 0) {
                v = Ylds[t*164 + pn];
            } else if (p == 1) {
                v = 0.f;
                #pragma unroll
                for (int j = 0; j < 3; ++j) {
                    const int tt = t + j - 1;
                    if (tt >= 0 && tt < 64) v = fmaf(Ylds[tt*164 + pn], k3[(g*32+n)*3 + j], v);
                }
            } else if (p == 2) {
                v = 0.f;
                #pragma unroll
                for (int j = 0; j < 5; ++j) {
                    const int tt = t + j - 2;
                    if (tt >= 0 && tt < 64) v = fmaf(Ylds[tt*164 + pn], k5[(g*32+n)*5 + j], v);
                }
            } else if (p == 3) {
                v = 0.f;
                #pragma unroll
                for (int j = 0; j < 7; ++j) {
                    const int tt = t + j - 3;
                    if (tt >= 0 && tt < 64) v = fmaf(Ylds[tt*164 + pn], k7[(g*32+n)*7 + j], v);
                }
            } else {
                const int t2 = (t < 63) ? t+1 : 63;
                v = fmaxf(Ylds[t*164 + pn], Ylds[t2*164 + pn]);
            }
            vv[q] = v;
        }
        const int pi = (p*8 + g)*32 + n;
        const float sc = gam[pi] * rsqrtf(var[pi] + EPSBN);
        const float sh = bet[pi] - mu[pi]*sc;
        const float r = fmaxf(fmaxf(fmaf(vv[0], sc, sh), fmaf(vv[1], sc, sh)), 0.f);
        z[((size_t)(b*32 + tq)*51 + s)*1280 + pn*8 + g] = r;
    }
}

// ---------------------------------------------------------------------------
// Layer 1: per-block (b, s<53, g<8).  A = z0 column (32 x 160), W = (160 x 200),
// N padded to 224 for the 16x16 thread grid (2 rows x 14 cols per thread).
// ---------------------------------------------------------------------------
__global__ __launch_bounds__(256) void tc_layer1(
    const float* __restrict__ zin, const float* __restrict__ ext,
    const float* __restrict__ w, const float* __restrict__ bias,
    const float* __restrict__ k3, const float* __restrict__ k5,
    const float* __restrict__ k7,
    const float* __restrict__ gam, const float* __restrict__ bet,
    const float* __restrict__ mu, const float* __restrict__ var,
    float* __restrict__ out)
{
    const int tid = threadIdx.x;
    const int g  = blockIdx.x & 7;
    const int bs = blockIdx.x >> 3;
    const int s  = bs % 53;
    const int b  = bs / 53;

    __shared__ float lds[32*164 + 32*224];      // 12416 floats = 49.7 KB
    float* Alds = lds;                          // 32 x 160, stride 164
    float* Blds = lds + 32*164;                 // 32 x 224
    float* Ylds = lds;                          // 32 x 200, stride 228 (overlap)

    // ---- load A (32 t x 160 k) ----
    #pragma unroll
    for (int it = 0; it < 5; ++it) {
        const int fid = tid + it*256;           // < 1280
        const int t  = fid / 40;
        const int k4 = (fid - t*40) * 4;
        const float* src = (s < 51)
            ? zin + ((size_t)(b*32 + t)*51 + s) * 1280 + g*160 + k4
            : ext + ((size_t)(b*32 + t)*2 + (s-51)) * 1280 + g*160 + k4;
        *reinterpret_cast<float4*>(&Alds[t*164 + k4]) = *reinterpret_cast<const float4*>(src);
    }

    const int ry = tid >> 4;                    // rows ry*2+i
    const int cx = tid & 15;                    // cols cx*14+j  (padded N=224)
    float acc[2][14];
    #pragma unroll
    for (int i = 0; i < 2; ++i)
        #pragma unroll
        for (int j = 0; j < 14; ++j) acc[i][j] = 0.f;

    for (int k0 = 0; k0 < 160; k0 += 32) {
        __syncthreads();
        #pragma unroll
        for (int it = 0; it < 28; ++it) {       // stage 32 x 224 W-chunk
            const int fid = tid + it*256;       // < 7168
            const int kk = fid / 224;
            const int c  = fid - kk*224;
            float v = 0.f;
            if (c < 200) {
                const int p = c / 40, n = c - p*40;
                v = w[(((size_t)p*8 + g)*160 + (k0+kk))*40 + n];
            }
            Blds[kk*224 + c] = v;
        }
        __syncthreads();
        #pragma unroll 8
        for (int kk = 0; kk < 32; ++kk) {
            const float a0 = Alds[(ry*2+0)*164 + k0+kk];
            const float a1 = Alds[(ry*2+1)*164 + k0+kk];
            const float2* br = reinterpret_cast<const float2*>(&Blds[kk*224 + cx*14]);
            const float2 q0 = br[0], q1 = br[1], q2 = br[2], q3 = br[3],
                         q4 = br[4], q5 = br[5], q6 = br[6];
            const float bb[14] = {q0.x,q0.y,q1.x,q1.y,q2.x,q2.y,q3.x,q3.y,
                                  q4.x,q4.y,q5.x,q5.y,q6.x,q6.y};
            #pragma unroll
            for (int j = 0; j < 14; ++j) {
                acc[0][j] = fmaf(a0, bb[j], acc[0][j]);
                acc[1][j] = fmaf(a1, bb[j], acc[1][j]);
            }
        }
    }
    __syncthreads();

    // ---- bias + stash Y (cols < 200 only) ----
    #pragma unroll
    for (int i = 0; i < 2; ++i) {
        const int row = ry*2 + i;
        #pragma unroll
        for (int j = 0; j < 14; ++j) {
            const int pn = cx*14 + j;
            if (pn < 200) {
                const int p = pn / 40, n = pn - p*40;
                Ylds[row*228 + pn] = acc[i][j] + bias[(p*8 + g)*40 + n];
            }
        }
    }
    __syncthreads();

    // ---- temporal branch + BN + relu + shuffle + T-pool(2) ----
    for (int oi = 0; oi < 13; ++oi) {
        const int idx = tid + oi*256;
        if (idx >= 3200) break;                 // 16*200 outputs
        const int tq = idx / 200;
        const int pn = idx - tq*200;
        const int p = pn / 40, n = pn - p*40;
        float vv[2];
        #pragma unroll
        for (int q = 0; q < 2; ++q) {
            const int t = 2*tq + q;
            float v;
            if (p == 0) {
                v = Ylds[t*228 + pn];
            } else if (p == 1) {
                v = 0.f;
                #pragma unroll
                for (int j = 0; j < 3; ++j) {
                    const int tt = t + j - 1;
                    if (tt >= 0 && tt < 32) v = fmaf(Ylds[tt*228 + pn], k3[(g*40+n)*3 + j], v);
                }
            } else if (p == 2) {
                v = 0.f;
                #pragma unroll
                for (int j = 0; j < 5; ++j) {
                    const int tt = t + j - 2;
                    if (tt >= 0 && tt < 32) v = fmaf(Ylds[tt*228 + pn], k5[(g*40+n)*5 + j], v);
                }
            } else if (p == 3) {
                v = 0.f;
                #pragma unroll
                for (int j = 0; j < 7; ++j) {
                    const int tt = t + j - 3;
                    if (tt >= 0 && tt < 32) v = fmaf(Ylds[tt*228 + pn], k7[(g*40+n)*7 + j], v);
                }
            } else {
                const int t2 = (t < 31) ? t+1 : 31;
                v = fmaxf(Ylds[t*228 + pn], Ylds[t2*228 + pn]);
            }
            vv[q] = v;
        }
        const int pi = (p*8 + g)*40 + n;
        const float sc = gam[pi] * rsqrtf(var[pi] + EPSBN);
        const float sh = bet[pi] - mu[pi]*sc;
        const float r = fmaxf(fmaxf(fmaf(vv[0], sc, sh), fmaf(vv[1], sc, sh)), 0.f);
        out[((size_t)(b*16 + tq)*53 + s)*1600 + pn*8 + g] = r;
    }
}

extern "C" void kernel_launch(void* const* d_in, const int* in_sizes, int n_in,
                              void* d_out, int out_size, void* d_ws, size_t ws_size,
                              hipStream_t stream) {
    const float* x    = (const float*)d_in[0];
    const float* w0   = (const float*)d_in[1];
    const float* b0   = (const float*)d_in[2];
    const float* k3_0 = (const float*)d_in[3];
    const float* k5_0 = (const float*)d_in[4];
    const float* k7_0 = (const float*)d_in[5];
    const float* g0   = (const float*)d_in[6];
    const float* be0  = (const float*)d_in[7];
    const float* mu0  = (const float*)d_in[8];
    const float* v0   = (const float*)d_in[9];
    const float* w1   = (const float*)d_in[10];
    const float* b1   = (const float*)d_in[11];
    const float* k3_1 = (const float*)d_in[12];
    const float* k5_1 = (const float*)d_in[13];
    const float* k7_1 = (const float*)d_in[14];
    const float* g1   = (const float*)d_in[15];
    const float* be1  = (const float*)d_in[16];
    const float* mu1  = (const float*)d_in[17];
    const float* v1   = (const float*)d_in[18];

    float* ws   = (float*)d_ws;
    float* ext0 = ws;                       // 16*64*2*1024  = 2,097,152 f
    float* z0   = ext0 + 2097152;           // 16*32*51*1280 = 33,423,360 f
    float* ext1 = z0 + 33423360;            // 16*32*2*1280  = 1,310,720 f
                                            // total 147.3 MB

    tc_reduce0<<<16*64, 256, 0, stream>>>(x, ext0);
    tc_layer0 <<<16*51*8, 256, 0, stream>>>(x, ext0, w0, b0, k3_0, k5_0, k7_0,
                                            g0, be0, mu0, v0, z0);
    tc_reduce1<<<16*32, 320, 0, stream>>>(z0, ext1);
    tc_layer1 <<<16*53*8, 256, 0, stream>>>(z0, ext1, w1, b1, k3_1, k5_1, k7_1,
                                            g1, be1, mu1, v1, (float*)d_out);
}

// Round 2
// 747.285 us; speedup vs baseline: 2.4217x; 2.4217x over previous
//
#include <hip/hip_runtime.h>
#include <hip/hip_bf16.h>

#define EPSBN 1e-3f

// ---------------------------------------------------------------------------
//   x    : (16, 64, 49, 1024) f32
//   ext0 : (16, 64, 2, 1024)  f32    [slot 0: max over s, slot 1: mean]
//   z0g  : (16, 32, 51, 1280) bf16   GROUP-MAJOR: ch = g0*160 + (p*32+n)
//   ext1 : (16, 32, 2, 1280)  bf16   same channel order as z0g
//   out  : (16, 16, 53, 1600) f32    written group-major by layer1
//                                    (ch = g1*200 + p*40+n), then shuffled
//                                    in place to reference order pq*8+g1.
// ---------------------------------------------------------------------------

__device__ __forceinline__ float bf2f(unsigned short u) {
    union { unsigned int i; float f; } c; c.i = (unsigned int)u << 16; return c.f;
}
__device__ __forceinline__ unsigned short f2bf(float f) {
    union { float f; unsigned int i; } c; c.f = f;
    unsigned int r = c.i + 0x7FFF + ((c.i >> 16) & 1);   // round-to-nearest-even
    return (unsigned short)(r >> 16);
}

__global__ __launch_bounds__(256) void tc_reduce0(const float* __restrict__ x,
                                                  float* __restrict__ ext) {
    const int bt = blockIdx.x;              // b*64+t
    const int c  = threadIdx.x * 4;
    const float4* src = reinterpret_cast<const float4*>(x + (size_t)bt * 49 * 1024 + c);
    float4 v = src[0];
    float mx0 = v.x, mx1 = v.y, mx2 = v.z, mx3 = v.w;
    float sm0 = v.x, sm1 = v.y, sm2 = v.z, sm3 = v.w;
    for (int s = 1; s < 49; ++s) {
        float4 u = src[(size_t)s * 256];
        mx0 = fmaxf(mx0, u.x); sm0 += u.x;
        mx1 = fmaxf(mx1, u.y); sm1 += u.y;
        mx2 = fmaxf(mx2, u.z); sm2 += u.z;
        mx3 = fmaxf(mx3, u.w); sm3 += u.w;
    }
    const float inv = 1.0f / 49.0f;
    float* d = ext + (size_t)bt * 2048 + c;
    *reinterpret_cast<float4*>(d)        = make_float4(mx0, mx1, mx2, mx3);
    *reinterpret_cast<float4*>(d + 1024) = make_float4(sm0*inv, sm1*inv, sm2*inv, sm3*inv);
}

__global__ __launch_bounds__(320) void tc_reduce1(const unsigned short* __restrict__ zb,
                                                  unsigned short* __restrict__ ext) {
    const int bt = blockIdx.x;              // b*32+t
    const int c  = threadIdx.x * 4;         // 0..1276
    const unsigned short* src = zb + (size_t)bt * 51 * 1280 + c;
    ushort4 u = *reinterpret_cast<const ushort4*>(src);
    float v0 = bf2f(u.x), v1 = bf2f(u.y), v2 = bf2f(u.z), v3 = bf2f(u.w);
    float mx0 = v0, mx1 = v1, mx2 = v2, mx3 = v3;
    float sm0 = v0, sm1 = v1, sm2 = v2, sm3 = v3;
    for (int s = 1; s < 51; ++s) {
        ushort4 w = *reinterpret_cast<const ushort4*>(src + (size_t)s * 1280);
        v0 = bf2f(w.x); v1 = bf2f(w.y); v2 = bf2f(w.z); v3 = bf2f(w.w);
        mx0 = fmaxf(mx0, v0); sm0 += v0;
        mx1 = fmaxf(mx1, v1); sm1 += v1;
        mx2 = fmaxf(mx2, v2); sm2 += v2;
        mx3 = fmaxf(mx3, v3); sm3 += v3;
    }
    const float inv = 1.0f / 51.0f;
    unsigned short* d = ext + (size_t)bt * 2560 + c;
    ushort4 o;
    o.x = f2bf(mx0); o.y = f2bf(mx1); o.z = f2bf(mx2); o.w = f2bf(mx3);
    *reinterpret_cast<ushort4*>(d) = o;
    o.x = f2bf(sm0*inv); o.y = f2bf(sm1*inv); o.z = f2bf(sm2*inv); o.w = f2bf(sm3*inv);
    *reinterpret_cast<ushort4*>(d + 1280) = o;
}

// ---------------------------------------------------------------------------
// Layer 0: block = (b, s<51, g<8).  A = x column (64x128) f32, W = (128x160),
// B staged in 16-row chunks.  Y (64x160) kept in LDS, temporal ops -> z0g bf16.
// ---------------------------------------------------------------------------
__global__ __launch_bounds__(256, 3) void tc_layer0(
    const float* __restrict__ x, const float* __restrict__ ext,
    const float* __restrict__ w, const float* __restrict__ bias,
    const float* __restrict__ k3, const float* __restrict__ k5,
    const float* __restrict__ k7,
    const float* __restrict__ gam, const float* __restrict__ bet,
    const float* __restrict__ mu, const float* __restrict__ var,
    unsigned short* __restrict__ zb)
{
    const int tid = threadIdx.x;
    const int g  = blockIdx.x & 7;
    const int bs = blockIdx.x >> 3;
    const int s  = bs % 51;
    const int b  = bs / 51;

    __shared__ float lds[64*132 + 16*160];      // 11008 floats = 44.0 KB
    float* Alds = lds;                          // 64 x 128, stride 132
    float* Blds = lds + 64*132;                 // 16 x 160
    float* Ylds = lds;                          // 64 x 160, stride 164 (overlay)

    // ---- load A (64 t x 128 k), float4 ----
    #pragma unroll
    for (int it = 0; it < 8; ++it) {
        const int fid = tid + it*256;           // < 2048
        const int t  = fid >> 5;
        const int k4 = (fid & 31) * 4;
        const float* src = (s < 49)
            ? x   + ((size_t)(b*64 + t)*49 + s) * 1024 + g*128 + k4
            : ext + ((size_t)(b*64 + t)*2 + (s-49)) * 1024 + g*128 + k4;
        *reinterpret_cast<float4*>(&Alds[t*132 + k4]) = *reinterpret_cast<const float4*>(src);
    }

    const int ry = tid >> 4;                    // rows ry*4+i
    const int cx = tid & 15;                    // cols cx*10+j
    float acc[4][10];
    #pragma unroll
    for (int i = 0; i < 4; ++i)
        #pragma unroll
        for (int j = 0; j < 10; ++j) acc[i][j] = 0.f;

    for (int k0 = 0; k0 < 128; k0 += 16) {
        __syncthreads();
        #pragma unroll
        for (int it = 0; it < 3; ++it) {        // stage 16 x 160 W-chunk, float4
            const int fid = tid + it*256;       // < 640
            if (fid < 640) {
                const int kk = fid / 40;
                const int c4 = (fid - kk*40) * 4;
                const float4 v = *reinterpret_cast<const float4*>(
                    &w[(((size_t)(c4 >> 5)*8 + g)*128 + (k0+kk))*32 + (c4 & 31)]);
                *reinterpret_cast<float4*>(&Blds[kk*160 + c4]) = v;
            }
        }
        __syncthreads();
        #pragma unroll
        for (int kk = 0; kk < 16; ++kk) {
            const float a0 = Alds[(ry*4+0)*132 + k0+kk];
            const float a1 = Alds[(ry*4+1)*132 + k0+kk];
            const float a2 = Alds[(ry*4+2)*132 + k0+kk];
            const float a3 = Alds[(ry*4+3)*132 + k0+kk];
            const float2* br = reinterpret_cast<const float2*>(&Blds[kk*160 + cx*10]);
            const float2 q0 = br[0], q1 = br[1], q2 = br[2], q3 = br[3], q4 = br[4];
            const float bb[10] = {q0.x,q0.y,q1.x,q1.y,q2.x,q2.y,q3.x,q3.y,q4.x,q4.y};
            #pragma unroll
            for (int j = 0; j < 10; ++j) {
                acc[0][j] = fmaf(a0, bb[j], acc[0][j]);
                acc[1][j] = fmaf(a1, bb[j], acc[1][j]);
                acc[2][j] = fmaf(a2, bb[j], acc[2][j]);
                acc[3][j] = fmaf(a3, bb[j], acc[3][j]);
            }
        }
    }
    __syncthreads();

    // ---- bias + stash Y ----
    #pragma unroll
    for (int i = 0; i < 4; ++i) {
        const int row = ry*4 + i;
        #pragma unroll
        for (int j = 0; j < 10; ++j) {
            const int pn = cx*10 + j;
            Ylds[row*164 + pn] = acc[i][j] + bias[((pn >> 5)*8 + g)*32 + (pn & 31)];
        }
    }
    __syncthreads();

    // ---- temporal branches (wave-uniform p) + BN + relu + T-pool(2) ----
    const int n   = tid & 31;
    const int tqb = tid >> 5;                   // 0..7
    const size_t zrow0 = ((size_t)(b*32)*51 + s)*1280 + g*160;

    // p = 0: identity
    {
        const int pi = g*32 + n;
        const float sc = gam[pi]*rsqrtf(var[pi]+EPSBN);
        const float sh = bet[pi] - mu[pi]*sc;
        #pragma unroll
        for (int it = 0; it < 4; ++it) {
            const int tq = tqb + it*8;
            const float u0 = Ylds[(2*tq  )*164 + n];
            const float u1 = Ylds[(2*tq+1)*164 + n];
            const float r = fmaxf(fmaxf(fmaf(u0,sc,sh), fmaf(u1,sc,sh)), 0.f);
            zb[zrow0 + (size_t)tq*51*1280 + n] = f2bf(r);
        }
    }
    // p = 1: dwconv k=3
    {
        const int pi = (8+g)*32 + n;
        const float sc = gam[pi]*rsqrtf(var[pi]+EPSBN);
        const float sh = bet[pi] - mu[pi]*sc;
        const float w0_ = k3[(g*32+n)*3+0], w1_ = k3[(g*32+n)*3+1], w2_ = k3[(g*32+n)*3+2];
        #pragma unroll
        for (int it = 0; it < 4; ++it) {
            const int tq = tqb + it*8;
            float vv[2];
            #pragma unroll
            for (int q = 0; q < 2; ++q) {
                const int t = 2*tq + q;
                float v = Ylds[t*164 + 32 + n] * w1_;
                if (t > 0)  v = fmaf(Ylds[(t-1)*164 + 32 + n], w0_, v);
                if (t < 63) v = fmaf(Ylds[(t+1)*164 + 32 + n], w2_, v);
                vv[q] = v;
            }
            const float r = fmaxf(fmaxf(fmaf(vv[0],sc,sh), fmaf(vv[1],sc,sh)), 0.f);
            zb[zrow0 + (size_t)tq*51*1280 + 32 + n] = f2bf(r);
        }
    }
    // p = 2: dwconv k=5
    {
        const int pi = (16+g)*32 + n;
        const float sc = gam[pi]*rsqrtf(var[pi]+EPSBN);
        const float sh = bet[pi] - mu[pi]*sc;
        float wk[5];
        #pragma unroll
        for (int j = 0; j < 5; ++j) wk[j] = k5[(g*32+n)*5+j];
        #pragma unroll
        for (int it = 0; it < 4; ++it) {
            const int tq = tqb + it*8;
            float vv[2];
            #pragma unroll
            for (int q = 0; q < 2; ++q) {
                const int t = 2*tq + q;
                float v = 0.f;
                #pragma unroll
                for (int j = 0; j < 5; ++j) {
                    const int tt = t + j - 2;
                    if (tt >= 0 && tt < 64) v = fmaf(Ylds[tt*164 + 64 + n], wk[j], v);
                }
                vv[q] = v;
            }
            const float r = fmaxf(fmaxf(fmaf(vv[0],sc,sh), fmaf(vv[1],sc,sh)), 0.f);
            zb[zrow0 + (size_t)tq*51*1280 + 64 + n] = f2bf(r);
        }
    }
    // p = 3: dwconv k=7
    {
        const int pi = (24+g)*32 + n;
        const float sc = gam[pi]*rsqrtf(var[pi]+EPSBN);
        const float sh = bet[pi] - mu[pi]*sc;
        float wk[7];
        #pragma unroll
        for (int j = 0; j < 7; ++j) wk[j] = k7[(g*32+n)*7+j];
        #pragma unroll
        for (int it = 0; it < 4; ++it) {
            const int tq = tqb + it*8;
            float vv[2];
            #pragma unroll
            for (int q = 0; q < 2; ++q) {
                const int t = 2*tq + q;
                float v = 0.f;
                #pragma unroll
                for (int j = 0; j < 7; ++j) {
                    const int tt = t + j - 3;
                    if (tt >= 0 && tt < 64) v = fmaf(Ylds[tt*164 + 96 + n], wk[j], v);
                }
                vv[q] = v;
            }
            const float r = fmaxf(fmaxf(fmaf(vv[0],sc,sh), fmaf(vv[1],sc,sh)), 0.f);
            zb[zrow0 + (size_t)tq*51*1280 + 96 + n] = f2bf(r);
        }
    }
    // p = 4: temporal maxpool(2, stride 1)
    {
        const int pi = (32+g)*32 + n;
        const float sc = gam[pi]*rsqrtf(var[pi]+EPSBN);
        const float sh = bet[pi] - mu[pi]*sc;
        #pragma unroll
        for (int it = 0; it < 4; ++it) {
            const int tq = tqb + it*8;
            float vv[2];
            #pragma unroll
            for (int q = 0; q < 2; ++q) {
                const int t = 2*tq + q;
                const int t2 = (t < 63) ? t+1 : 63;
                vv[q] = fmaxf(Ylds[t*164 + 128 + n], Ylds[t2*164 + 128 + n]);
            }
            const float r = fmaxf(fmaxf(fmaf(vv[0],sc,sh), fmaf(vv[1],sc,sh)), 0.f);
            zb[zrow0 + (size_t)tq*51*1280 + 128 + n] = f2bf(r);
        }
    }
}

// ---------------------------------------------------------------------------
// Layer 1: block = (b, s<53, g<8).  A (32x160) gathered from group-major z0g
// (k-permuted); W k-rows permuted identically.  Writes d_out group-major.
// ---------------------------------------------------------------------------
__global__ __launch_bounds__(256, 4) void tc_layer1(
    const unsigned short* __restrict__ zb, const unsigned short* __restrict__ ext,
    const float* __restrict__ w, const float* __restrict__ bias,
    const float* __restrict__ k3, const float* __restrict__ k5,
    const float* __restrict__ k7,
    const float* __restrict__ gam, const float* __restrict__ bet,
    const float* __restrict__ mu, const float* __restrict__ var,
    float* __restrict__ out)
{
    const int tid = threadIdx.x;
    const int g  = blockIdx.x & 7;
    const int bs = blockIdx.x >> 3;
    const int s  = bs % 53;
    const int b  = bs / 53;

    __shared__ float lds[32*164 + 16*224];      // 8832 floats = 35.3 KB
    float* Alds = lds;                          // 32 x 160, stride 164 (z0g k-order)
    float* Blds = lds + 32*164;                 // 16 x 224 (cols >=200 garbage, unused)
    float* Ylds = lds;                          // 32 x 200, stride 228 (overlay)

    // ---- gather A (32 t x 160 k in z0g order), ushort4 -> float4 ----
    #pragma unroll
    for (int it = 0; it < 5; ++it) {
        const int fid = tid + it*256;           // < 1280
        const int t   = fid / 40;
        const int seg = fid - t*40;
        const int gg  = seg / 5, q = seg - gg*5;
        const int ch  = gg*160 + g*20 + q*4;
        const unsigned short* src = (s < 51)
            ? zb  + ((size_t)(b*32 + t)*51 + s) * 1280 + ch
            : ext + ((size_t)(b*32 + t)*2 + (s-51)) * 1280 + ch;
        const ushort4 u = *reinterpret_cast<const ushort4*>(src);
        *reinterpret_cast<float4*>(&Alds[t*164 + gg*20 + q*4]) =
            make_float4(bf2f(u.x), bf2f(u.y), bf2f(u.z), bf2f(u.w));
    }

    const int ry = tid >> 4;                    // rows ry*2+i
    const int cx = tid & 15;                    // cols cx*14+j (N padded to 224)
    float acc[2][14];
    #pragma unroll
    for (int i = 0; i < 2; ++i)
        #pragma unroll
        for (int j = 0; j < 14; ++j) acc[i][j] = 0.f;

    for (int k0 = 0; k0 < 160; k0 += 16) {
        __syncthreads();
        #pragma unroll
        for (int it = 0; it < 4; ++it) {        // stage 16 x 200 W-chunk, float4
            const int fid = tid + it*256;       // < 800
            if (fid < 800) {
                const int kk = fid / 50;
                const int c4 = (fid - kk*50) * 4;
                const int kr = k0 + kk;
                const int kd = kr / 20;
                const int kref = (kr - kd*20)*8 + kd;       // permuted k row
                const int p = c4 / 40, n = c4 - p*40;
                const float4 v = *reinterpret_cast<const float4*>(
                    &w[(((size_t)p*8 + g)*160 + kref)*40 + n]);
                *reinterpret_cast<float4*>(&Blds[kk*224 + c4]) = v;
            }
        }
        __syncthreads();
        #pragma unroll
        for (int kk = 0; kk < 16; ++kk) {
            const float a0 = Alds[(ry*2+0)*164 + k0+kk];
            const float a1 = Alds[(ry*2+1)*164 + k0+kk];
            const float2* br = reinterpret_cast<const float2*>(&Blds[kk*224 + cx*14]);
            const float2 q0 = br[0], q1 = br[1], q2 = br[2], q3 = br[3],
                         q4 = br[4], q5 = br[5], q6 = br[6];
            const float bb[14] = {q0.x,q0.y,q1.x,q1.y,q2.x,q2.y,q3.x,q3.y,
                                  q4.x,q4.y,q5.x,q5.y,q6.x,q6.y};
            #pragma unroll
            for (int j = 0; j < 14; ++j) {
                acc[0][j] = fmaf(a0, bb[j], acc[0][j]);
                acc[1][j] = fmaf(a1, bb[j], acc[1][j]);
            }
        }
    }
    __syncthreads();

    // ---- bias + stash Y (cols < 200) ----
    #pragma unroll
    for (int i = 0; i < 2; ++i) {
        const int row = ry*2 + i;
        #pragma unroll
        for (int j = 0; j < 14; ++j) {
            const int pn = cx*14 + j;
            if (pn < 200) {
                const int p = pn / 40, n = pn - p*40;
                Ylds[row*228 + pn] = acc[i][j] + bias[(p*8 + g)*40 + n];
            }
        }
    }
    __syncthreads();

    // ---- temporal branches (wave-uniform p) + BN + relu + T-pool(2) ----
    const size_t orow0 = ((size_t)(b*16)*53 + s)*1600 + g*200;

    #pragma unroll
    for (int p = 0; p < 5; ++p) {
        for (int it = 0; it < 3; ++it) {
            const int idx = tid + it*256;       // < 640 = 16tq * 40n
            if (idx < 640) {
                const int tq = idx / 40;
                const int n  = idx - tq*40;
                const int pn = p*40 + n;
                float vv[2];
                #pragma unroll
                for (int q = 0; q < 2; ++q) {
                    const int t = 2*tq + q;
                    float v;
                    if (p == 0) {
                        v = Ylds[t*228 + pn];
                    } else if (p == 1) {
                        v = Ylds[t*228 + pn] * k3[(g*40+n)*3+1];
                        if (t > 0)  v = fmaf(Ylds[(t-1)*228 + pn], k3[(g*40+n)*3+0], v);
                        if (t < 31) v = fmaf(Ylds[(t+1)*228 + pn], k3[(g*40+n)*3+2], v);
                    } else if (p == 2) {
                        v = 0.f;
                        #pragma unroll
                        for (int j = 0; j < 5; ++j) {
                            const int tt = t + j - 2;
                            if (tt >= 0 && tt < 32) v = fmaf(Ylds[tt*228 + pn], k5[(g*40+n)*5+j], v);
                        }
                    } else if (p == 3) {
                        v = 0.f;
                        #pragma unroll
                        for (int j = 0; j < 7; ++j) {
                            const int tt = t + j - 3;
                            if (tt >= 0 && tt < 32) v = fmaf(Ylds[tt*228 + pn], k7[(g*40+n)*7+j], v);
                        }
                    } else {
                        const int t2 = (t < 31) ? t+1 : 31;
                        v = fmaxf(Ylds[t*228 + pn], Ylds[t2*228 + pn]);
                    }
                    vv[q] = v;
                }
                const int pi = (p*8 + g)*40 + n;
                const float sc = gam[pi]*rsqrtf(var[pi]+EPSBN);
                const float sh = bet[pi] - mu[pi]*sc;
                const float r = fmaxf(fmaxf(fmaf(vv[0],sc,sh), fmaf(vv[1],sc,sh)), 0.f);
                out[orow0 + (size_t)tq*53*1600 + pn] = r;
            }
        }
    }
}

// ---------------------------------------------------------------------------
// In-place channel shuffle of d_out rows: group-major (g*200+pq) -> pq*8+g
// ---------------------------------------------------------------------------
__global__ __launch_bounds__(256) void tc_shuffle(float* __restrict__ o) {
    __shared__ float row[1600];
    const size_t base = (size_t)blockIdx.x * 1600;
    const int tid = threadIdx.x;
    #pragma unroll
    for (int it = 0; it < 2; ++it) {
        const int f4 = tid + it*256;
        if (f4 < 400)
            *reinterpret_cast<float4*>(&row[f4*4]) =
                *reinterpret_cast<const float4*>(&o[base + (size_t)f4*4]);
    }
    __syncthreads();
    #pragma unroll
    for (int it = 0; it < 2; ++it) {
        const int f4 = tid + it*256;
        if (f4 < 400) {
            const int c = f4*4;
            float4 v;
            v.x = row[((c  ) & 7)*200 + ((c  ) >> 3)];
            v.y = row[((c+1) & 7)*200 + ((c+1) >> 3)];
            v.z = row[((c+2) & 7)*200 + ((c+2) >> 3)];
            v.w = row[((c+3) & 7)*200 + ((c+3) >> 3)];
            *reinterpret_cast<float4*>(&o[base + (size_t)c]) = v;
        }
    }
}

extern "C" void kernel_launch(void* const* d_in, const int* in_sizes, int n_in,
                              void* d_out, int out_size, void* d_ws, size_t ws_size,
                              hipStream_t stream) {
    const float* x    = (const float*)d_in[0];
    const float* w0   = (const float*)d_in[1];
    const float* b0   = (const float*)d_in[2];
    const float* k3_0 = (const float*)d_in[3];
    const float* k5_0 = (const float*)d_in[4];
    const float* k7_0 = (const float*)d_in[5];
    const float* g0   = (const float*)d_in[6];
    const float* be0  = (const float*)d_in[7];
    const float* mu0  = (const float*)d_in[8];
    const float* v0   = (const float*)d_in[9];
    const float* w1   = (const float*)d_in[10];
    const float* b1   = (const float*)d_in[11];
    const float* k3_1 = (const float*)d_in[12];
    const float* k5_1 = (const float*)d_in[13];
    const float* k7_1 = (const float*)d_in[14];
    const float* g1   = (const float*)d_in[15];
    const float* be1  = (const float*)d_in[16];
    const float* mu1  = (const float*)d_in[17];
    const float* v1   = (const float*)d_in[18];

    float* ext0          = (float*)d_ws;                       // 2,097,152 f32 (8.4 MB)
    unsigned short* zb   = (unsigned short*)(ext0 + 2097152);  // 33,423,360 bf16 (66.8 MB)
    unsigned short* e1   = zb + 33423360;                      // 1,310,720 bf16 (2.6 MB)

    tc_reduce0<<<16*64, 256, 0, stream>>>(x, ext0);
    tc_layer0 <<<16*51*8, 256, 0, stream>>>(x, ext0, w0, b0, k3_0, k5_0, k7_0,
                                            g0, be0, mu0, v0, zb);
    tc_reduce1<<<16*32, 320, 0, stream>>>(zb, e1);
    tc_layer1 <<<16*53*8, 256, 0, stream>>>(zb, e1, w1, b1, k3_1, k5_1, k7_1,
                                            g1, be1, mu1, v1, (float*)d_out);
    tc_shuffle<<<16*16*53, 256, 0, stream>>>((float*)d_out);
}

// Round 3
// 357.419 us; speedup vs baseline: 5.0633x; 2.0908x over previous
//
#include <hip/hip_runtime.h>
#include <hip/hip_bf16.h>

#define EPSBN 1e-3f

typedef __attribute__((ext_vector_type(8))) short bf16x8;
typedef __attribute__((ext_vector_type(4))) float f32x4;

// ---------------------------------------------------------------------------
//   x    : (16, 64, 49, 1024) f32
//   ext0 : (16, 64, 2, 1024)  f32    [slot 0: max over s, slot 1: mean]
//   z0g  : (16, 32, 51, 1280) bf16   GROUP-MAJOR: ch = g0*160 + (p*32+n)
//   ext1 : (16, 32, 2, 1280)  bf16
//   out  : (16, 16, 53, 1600) f32    group-major (g1*200 + p*40+n), then
//                                    shuffled in place to ref order pq*8+g1.
// ---------------------------------------------------------------------------

__device__ __forceinline__ float bf2f(unsigned short u) {
    union { unsigned int i; float f; } c; c.i = (unsigned int)u << 16; return c.f;
}
__device__ __forceinline__ unsigned short f2bf(float f) {
    union { float f; unsigned int i; } c; c.f = f;
    unsigned int r = c.i + 0x7FFF + ((c.i >> 16) & 1);   // RNE
    return (unsigned short)(r >> 16);
}

__global__ __launch_bounds__(256) void tc_reduce0(const float* __restrict__ x,
                                                  float* __restrict__ ext) {
    const int bt = blockIdx.x;              // b*64+t
    const int c  = threadIdx.x * 4;
    const float4* src = reinterpret_cast<const float4*>(x + (size_t)bt * 49 * 1024 + c);
    float4 v = src[0];
    float mx0 = v.x, mx1 = v.y, mx2 = v.z, mx3 = v.w;
    float sm0 = v.x, sm1 = v.y, sm2 = v.z, sm3 = v.w;
    for (int s = 1; s < 49; ++s) {
        float4 u = src[(size_t)s * 256];
        mx0 = fmaxf(mx0, u.x); sm0 += u.x;
        mx1 = fmaxf(mx1, u.y); sm1 += u.y;
        mx2 = fmaxf(mx2, u.z); sm2 += u.z;
        mx3 = fmaxf(mx3, u.w); sm3 += u.w;
    }
    const float inv = 1.0f / 49.0f;
    float* d = ext + (size_t)bt * 2048 + c;
    *reinterpret_cast<float4*>(d)        = make_float4(mx0, mx1, mx2, mx3);
    *reinterpret_cast<float4*>(d + 1024) = make_float4(sm0*inv, sm1*inv, sm2*inv, sm3*inv);
}

__global__ __launch_bounds__(320) void tc_reduce1(const unsigned short* __restrict__ zb,
                                                  unsigned short* __restrict__ ext) {
    const int bt = blockIdx.x;              // b*32+t
    const int c  = threadIdx.x * 4;         // 0..1276
    const unsigned short* src = zb + (size_t)bt * 51 * 1280 + c;
    ushort4 u = *reinterpret_cast<const ushort4*>(src);
    float v0 = bf2f(u.x), v1 = bf2f(u.y), v2 = bf2f(u.z), v3 = bf2f(u.w);
    float mx0 = v0, mx1 = v1, mx2 = v2, mx3 = v3;
    float sm0 = v0, sm1 = v1, sm2 = v2, sm3 = v3;
    for (int s = 1; s < 51; ++s) {
        ushort4 w = *reinterpret_cast<const ushort4*>(src + (size_t)s * 1280);
        v0 = bf2f(w.x); v1 = bf2f(w.y); v2 = bf2f(w.z); v3 = bf2f(w.w);
        mx0 = fmaxf(mx0, v0); sm0 += v0;
        mx1 = fmaxf(mx1, v1); sm1 += v1;
        mx2 = fmaxf(mx2, v2); sm2 += v2;
        mx3 = fmaxf(mx3, v3); sm3 += v3;
    }
    const float inv = 1.0f / 51.0f;
    unsigned short* d = ext + (size_t)bt * 2560 + c;
    ushort4 o;
    o.x = f2bf(mx0); o.y = f2bf(mx1); o.z = f2bf(mx2); o.w = f2bf(mx3);
    *reinterpret_cast<ushort4*>(d) = o;
    o.x = f2bf(sm0*inv); o.y = f2bf(sm1*inv); o.z = f2bf(sm2*inv); o.w = f2bf(sm3*inv);
    *reinterpret_cast<ushort4*>(d + 1280) = o;
}

// ---------------------------------------------------------------------------
// Layer 0: block (b, s<51, g<8).  MFMA: D = W^T x A^T -> Yt[n][t].
//   A-operand = Wt [160 n][k] bf16, B-operand = At [64 t][k] bf16.
// ---------------------------------------------------------------------------
__global__ __launch_bounds__(256, 3) void tc_layer0(
    const float* __restrict__ x, const float* __restrict__ ext,
    const float* __restrict__ w, const float* __restrict__ bias,
    const float* __restrict__ k3, const float* __restrict__ k5,
    const float* __restrict__ k7,
    const float* __restrict__ gam, const float* __restrict__ bet,
    const float* __restrict__ mu, const float* __restrict__ var,
    unsigned short* __restrict__ zb)
{
    const int tid = threadIdx.x;
    const int g  = blockIdx.x / 816;
    const int bs = blockIdx.x % 816;
    const int s  = bs % 51;
    const int b  = bs / 51;

    __shared__ float ldsf[10880];                       // 43.5 KB
    unsigned short* AtU = (unsigned short*)ldsf;        // 64 x 136 bf16
    unsigned short* WtU = AtU + 64*136;                 // 160 x 40 bf16 (k-chunk)
    float* Yt = ldsf;                                   // 160 x 68 f32 (overlay)

    // ---- stage At (64 t x 128 k) f32 -> bf16 ----
    #pragma unroll
    for (int it = 0; it < 8; ++it) {
        const int fid = tid + it*256;           // < 2048
        const int t  = fid >> 5;
        const int k4 = (fid & 31) * 4;
        const float* src = (s < 49)
            ? x   + ((size_t)(b*64 + t)*49 + s) * 1024 + g*128 + k4
            : ext + ((size_t)(b*64 + t)*2 + (s-49)) * 1024 + g*128 + k4;
        const float4 v = *reinterpret_cast<const float4*>(src);
        ushort4 u;
        u.x = f2bf(v.x); u.y = f2bf(v.y); u.z = f2bf(v.z); u.w = f2bf(v.w);
        *reinterpret_cast<ushort4*>(&AtU[t*136 + k4]) = u;
    }

    const int lane = tid & 63;
    const int wid  = tid >> 6;              // wave = t-tile (0..3)
    const int fr   = lane & 15;
    const int kb   = lane >> 4;

    f32x4 zero = {0.f, 0.f, 0.f, 0.f};
    f32x4 acc[10];
    #pragma unroll
    for (int i = 0; i < 10; ++i) acc[i] = zero;

    for (int kc = 0; kc < 4; ++kc) {
        __syncthreads();
        // stage Wt chunk: 32 k x 160 n, transposed to [n][k] bf16
        #pragma unroll
        for (int it = 0; it < 5; ++it) {
            const int gi = tid + it*256;        // < 1280
            const int kg = gi / 160;            // 0..7 (4-k group)
            const int nf = gi - kg*160;         // 0..159
            const int p  = nf >> 5, nn = nf & 31;
            const float* wp = &w[(((size_t)p*8 + g)*128 + kc*32 + kg*4)*32 + nn];
            ushort4 u;
            u.x = f2bf(wp[0]); u.y = f2bf(wp[32]); u.z = f2bf(wp[64]); u.w = f2bf(wp[96]);
            *reinterpret_cast<ushort4*>(&WtU[nf*40 + kg*4]) = u;
        }
        __syncthreads();
        const bf16x8 bfrag = *reinterpret_cast<const bf16x8*>(
            &AtU[(wid*16 + fr)*136 + kc*32 + kb*8]);
        #pragma unroll
        for (int nt = 0; nt < 10; ++nt) {
            const bf16x8 afrag = *reinterpret_cast<const bf16x8*>(
                &WtU[(nt*16 + fr)*40 + kb*8]);
            acc[nt] = __builtin_amdgcn_mfma_f32_16x16x32_bf16(afrag, bfrag, acc[nt], 0, 0, 0);
        }
    }
    __syncthreads();
    // D: row(n) = nt*16 + kb*4 + r, col(t) = wid*16 + fr
    #pragma unroll
    for (int nt = 0; nt < 10; ++nt)
        #pragma unroll
        for (int r = 0; r < 4; ++r)
            Yt[(nt*16 + kb*4 + r)*68 + wid*16 + fr] = acc[nt][r];
    __syncthreads();

    // ---- epilogue: one thread per channel, contiguous-t register sweep ----
    if (tid < 160) {
        const int ch = tid;
        const int p  = ch >> 5, n = ch & 31;
        const int pi = (p*8 + g)*32 + n;
        const float bsv = bias[pi];
        const float sc  = gam[pi]*rsqrtf(var[pi]+EPSBN);
        const float sh  = bet[pi] - mu[pi]*sc;
        float yv[64];
        const float4* yr = reinterpret_cast<const float4*>(&Yt[ch*68]);
        #pragma unroll
        for (int i = 0; i < 16; ++i) {
            const float4 v = yr[i];
            yv[4*i+0] = v.x + bsv; yv[4*i+1] = v.y + bsv;
            yv[4*i+2] = v.z + bsv; yv[4*i+3] = v.w + bsv;
        }
        unsigned short* zp = zb + ((size_t)(b*32)*51 + s)*1280 + g*160 + ch;
        if (p == 0) {
            #pragma unroll
            for (int tq = 0; tq < 32; ++tq) {
                const float r = fmaxf(fmaxf(fmaf(yv[2*tq],sc,sh), fmaf(yv[2*tq+1],sc,sh)), 0.f);
                zp[(size_t)tq*65280] = f2bf(r);
            }
        } else if (p == 1) {
            const float w0_ = k3[(g*32+n)*3+0], w1_ = k3[(g*32+n)*3+1], w2_ = k3[(g*32+n)*3+2];
            #pragma unroll
            for (int tq = 0; tq < 32; ++tq) {
                float a = yv[2*tq]*w1_;
                if (tq > 0) a = fmaf(yv[2*tq-1], w0_, a);
                a = fmaf(yv[2*tq+1], w2_, a);
                float c2 = fmaf(yv[2*tq], w0_, yv[2*tq+1]*w1_);
                if (tq < 31) c2 = fmaf(yv[2*tq+2], w2_, c2);
                const float r = fmaxf(fmaxf(fmaf(a,sc,sh), fmaf(c2,sc,sh)), 0.f);
                zp[(size_t)tq*65280] = f2bf(r);
            }
        } else if (p == 2) {
            float wk[5];
            #pragma unroll
            for (int j = 0; j < 5; ++j) wk[j] = k5[(g*32+n)*5+j];
            #pragma unroll
            for (int tq = 0; tq < 32; ++tq) {
                float vv[2];
                #pragma unroll
                for (int q = 0; q < 2; ++q) {
                    const int t = 2*tq + q;
                    float v = 0.f;
                    #pragma unroll
                    for (int j = 0; j < 5; ++j) {
                        const int ttp = t + j - 2;
                        if (ttp >= 0 && ttp < 64) v = fmaf(yv[ttp], wk[j], v);
                    }
                    vv[q] = v;
                }
                const float r = fmaxf(fmaxf(fmaf(vv[0],sc,sh), fmaf(vv[1],sc,sh)), 0.f);
                zp[(size_t)tq*65280] = f2bf(r);
            }
        } else if (p == 3) {
            float wk[7];
            #pragma unroll
            for (int j = 0; j < 7; ++j) wk[j] = k7[(g*32+n)*7+j];
            #pragma unroll
            for (int tq = 0; tq < 32; ++tq) {
                float vv[2];
                #pragma unroll
                for (int q = 0; q < 2; ++q) {
                    const int t = 2*tq + q;
                    float v = 0.f;
                    #pragma unroll
                    for (int j = 0; j < 7; ++j) {
                        const int ttp = t + j - 3;
                        if (ttp >= 0 && ttp < 64) v = fmaf(yv[ttp], wk[j], v);
                    }
                    vv[q] = v;
                }
                const float r = fmaxf(fmaxf(fmaf(vv[0],sc,sh), fmaf(vv[1],sc,sh)), 0.f);
                zp[(size_t)tq*65280] = f2bf(r);
            }
        } else {
            #pragma unroll
            for (int tq = 0; tq < 32; ++tq) {
                const float v0 = fmaxf(yv[2*tq], yv[2*tq+1]);
                const float v1 = fmaxf(yv[2*tq+1], yv[(2*tq+2 < 64) ? 2*tq+2 : 63]);
                const float r = fmaxf(fmaxf(fmaf(v0,sc,sh), fmaf(v1,sc,sh)), 0.f);
                zp[(size_t)tq*65280] = f2bf(r);
            }
        }
    }
}

// ---------------------------------------------------------------------------
// Layer 1: block (b, s<53, g<8).  Same MFMA scheme; A gathered from z0g
// (k-permuted), W k-rows permuted identically (kref = (kr%20)*8 + kr/20).
// ---------------------------------------------------------------------------
__global__ __launch_bounds__(256, 4) void tc_layer1(
    const unsigned short* __restrict__ zbi, const unsigned short* __restrict__ ext,
    const float* __restrict__ w, const float* __restrict__ bias,
    const float* __restrict__ k3, const float* __restrict__ k5,
    const float* __restrict__ k7,
    const float* __restrict__ gam, const float* __restrict__ bet,
    const float* __restrict__ mu, const float* __restrict__ var,
    float* __restrict__ out)
{
    const int tid = threadIdx.x;
    const int g  = blockIdx.x / 848;        // same-(b,s) blocks = same XCD
    const int bs = blockIdx.x % 848;
    const int s  = bs % 53;
    const int b  = bs / 53;

    __shared__ float ldsf[7200];                        // 28.8 KB
    unsigned short* AtU = (unsigned short*)ldsf;        // 32 x 168 bf16
    unsigned short* WtU = AtU + 32*168;                 // 208 x 40 bf16 (k-chunk)
    float* Yt = ldsf;                                   // 200 x 36 f32 (overlay)

    // ---- gather At (32 t x 160 k, z0g k-order) bf16 ----
    #pragma unroll
    for (int it = 0; it < 5; ++it) {
        const int fid = tid + it*256;           // < 1280
        const int t   = fid / 40;
        const int seg = fid - t*40;
        const int gg  = seg / 5, q = seg - gg*5;
        const int ch  = gg*160 + g*20 + q*4;
        const unsigned short* src = (s < 51)
            ? zbi + ((size_t)(b*32 + t)*51 + s) * 1280 + ch
            : ext + ((size_t)(b*32 + t)*2 + (s-51)) * 1280 + ch;
        *reinterpret_cast<ushort4*>(&AtU[t*168 + seg*4]) =
            *reinterpret_cast<const ushort4*>(src);
    }

    const int lane = tid & 63;
    const int wid  = tid >> 6;
    const int tt_  = wid & 1;               // t-tile
    const int nh   = wid >> 1;              // n-half
    const int nbase = nh * 7;               // nh0: nt 0..6, nh1: nt 7..12
    const int fr   = lane & 15;
    const int kb   = lane >> 4;

    f32x4 zero = {0.f, 0.f, 0.f, 0.f};
    f32x4 acc[7];
    #pragma unroll
    for (int i = 0; i < 7; ++i) acc[i] = zero;

    for (int kc = 0; kc < 5; ++kc) {
        __syncthreads();
        // stage Wt chunk: 32 permuted-k x 200 n -> [n][k] bf16
        #pragma unroll
        for (int it = 0; it < 7; ++it) {
            const int gi = tid + it*256;
            if (gi < 1600) {
                const int kg = gi / 200;
                const int nf = gi - kg*200;
                const int p  = nf / 40, nn = nf - p*40;
                const int kr0 = kc*32 + kg*4;
                const int blk = kr0 / 20;
                const int m0  = kr0 - blk*20;   // kref = (m0+j)*8 + blk
                const float* wp = &w[(((size_t)p*8 + g)*160 + m0*8 + blk)*40 + nn];
                ushort4 u;
                u.x = f2bf(wp[0]); u.y = f2bf(wp[320]); u.z = f2bf(wp[640]); u.w = f2bf(wp[960]);
                *reinterpret_cast<ushort4*>(&WtU[nf*40 + kg*4]) = u;
            }
        }
        __syncthreads();
        const bf16x8 bfrag = *reinterpret_cast<const bf16x8*>(
            &AtU[(tt_*16 + fr)*168 + kc*32 + kb*8]);
        #pragma unroll
        for (int i = 0; i < 7; ++i) {
            const int nt = nbase + i;
            if (nt < 13) {
                const bf16x8 afrag = *reinterpret_cast<const bf16x8*>(
                    &WtU[(nt*16 + fr)*40 + kb*8]);
                acc[i] = __builtin_amdgcn_mfma_f32_16x16x32_bf16(afrag, bfrag, acc[i], 0, 0, 0);
            }
        }
    }
    __syncthreads();
    #pragma unroll
    for (int i = 0; i < 7; ++i) {
        const int nt = nbase + i;
        if (nt < 13) {
            #pragma unroll
            for (int r = 0; r < 4; ++r) {
                const int row = nt*16 + kb*4 + r;
                if (row < 200) Yt[row*36 + tt_*16 + fr] = acc[i][r];
            }
        }
    }
    __syncthreads();

    if (tid < 200) {
        const int ch = tid;
        const int p  = ch / 40, n = ch - p*40;
        const int pi = (p*8 + g)*40 + n;
        const float bsv = bias[pi];
        const float sc  = gam[pi]*rsqrtf(var[pi]+EPSBN);
        const float sh  = bet[pi] - mu[pi]*sc;
        float yv[32];
        const float4* yr = reinterpret_cast<const float4*>(&Yt[ch*36]);
        #pragma unroll
        for (int i = 0; i < 8; ++i) {
            const float4 v = yr[i];
            yv[4*i+0] = v.x + bsv; yv[4*i+1] = v.y + bsv;
            yv[4*i+2] = v.z + bsv; yv[4*i+3] = v.w + bsv;
        }
        float* op = out + ((size_t)(b*16)*53 + s)*1600 + g*200 + ch;
        if (p == 0) {
            #pragma unroll
            for (int tq = 0; tq < 16; ++tq)
                op[(size_t)tq*84800] =
                    fmaxf(fmaxf(fmaf(yv[2*tq],sc,sh), fmaf(yv[2*tq+1],sc,sh)), 0.f);
        } else if (p == 1) {
            const float w0_ = k3[(g*40+n)*3+0], w1_ = k3[(g*40+n)*3+1], w2_ = k3[(g*40+n)*3+2];
            #pragma unroll
            for (int tq = 0; tq < 16; ++tq) {
                float a = yv[2*tq]*w1_;
                if (tq > 0) a = fmaf(yv[2*tq-1], w0_, a);
                a = fmaf(yv[2*tq+1], w2_, a);
                float c2 = fmaf(yv[2*tq], w0_, yv[2*tq+1]*w1_);
                if (tq < 15) c2 = fmaf(yv[2*tq+2], w2_, c2);
                op[(size_t)tq*84800] = fmaxf(fmaxf(fmaf(a,sc,sh), fmaf(c2,sc,sh)), 0.f);
            }
        } else if (p == 2) {
            float wk[5];
            #pragma unroll
            for (int j = 0; j < 5; ++j) wk[j] = k5[(g*40+n)*5+j];
            #pragma unroll
            for (int tq = 0; tq < 16; ++tq) {
                float vv[2];
                #pragma unroll
                for (int q = 0; q < 2; ++q) {
                    const int t = 2*tq + q;
                    float v = 0.f;
                    #pragma unroll
                    for (int j = 0; j < 5; ++j) {
                        const int ttp = t + j - 2;
                        if (ttp >= 0 && ttp < 32) v = fmaf(yv[ttp], wk[j], v);
                    }
                    vv[q] = v;
                }
                op[(size_t)tq*84800] = fmaxf(fmaxf(fmaf(vv[0],sc,sh), fmaf(vv[1],sc,sh)), 0.f);
            }
        } else if (p == 3) {
            float wk[7];
            #pragma unroll
            for (int j = 0; j < 7; ++j) wk[j] = k7[(g*40+n)*7+j];
            #pragma unroll
            for (int tq = 0; tq < 16; ++tq) {
                float vv[2];
                #pragma unroll
                for (int q = 0; q < 2; ++q) {
                    const int t = 2*tq + q;
                    float v = 0.f;
                    #pragma unroll
                    for (int j = 0; j < 7; ++j) {
                        const int ttp = t + j - 3;
                        if (ttp >= 0 && ttp < 32) v = fmaf(yv[ttp], wk[j], v);
                    }
                    vv[q] = v;
                }
                op[(size_t)tq*84800] = fmaxf(fmaxf(fmaf(vv[0],sc,sh), fmaf(vv[1],sc,sh)), 0.f);
            }
        } else {
            #pragma unroll
            for (int tq = 0; tq < 16; ++tq) {
                const float v0 = fmaxf(yv[2*tq], yv[2*tq+1]);
                const float v1 = fmaxf(yv[2*tq+1], yv[(2*tq+2 < 32) ? 2*tq+2 : 31]);
                op[(size_t)tq*84800] = fmaxf(fmaxf(fmaf(v0,sc,sh), fmaf(v1,sc,sh)), 0.f);
            }
        }
    }
}

// ---------------------------------------------------------------------------
// In-place channel shuffle of d_out rows: group-major (g*200+pq) -> pq*8+g
// ---------------------------------------------------------------------------
__global__ __launch_bounds__(256) void tc_shuffle(float* __restrict__ o) {
    __shared__ float row[1600];
    const size_t base = (size_t)blockIdx.x * 1600;
    const int tid = threadIdx.x;
    #pragma unroll
    for (int it = 0; it < 2; ++it) {
        const int f4 = tid + it*256;
        if (f4 < 400)
            *reinterpret_cast<float4*>(&row[f4*4]) =
                *reinterpret_cast<const float4*>(&o[base + (size_t)f4*4]);
    }
    __syncthreads();
    #pragma unroll
    for (int it = 0; it < 2; ++it) {
        const int f4 = tid + it*256;
        if (f4 < 400) {
            const int c = f4*4;
            float4 v;
            v.x = row[((c  ) & 7)*200 + ((c  ) >> 3)];
            v.y = row[((c+1) & 7)*200 + ((c+1) >> 3)];
            v.z = row[((c+2) & 7)*200 + ((c+2) >> 3)];
            v.w = row[((c+3) & 7)*200 + ((c+3) >> 3)];
            *reinterpret_cast<float4*>(&o[base + (size_t)c]) = v;
        }
    }
}

extern "C" void kernel_launch(void* const* d_in, const int* in_sizes, int n_in,
                              void* d_out, int out_size, void* d_ws, size_t ws_size,
                              hipStream_t stream) {
    const float* x    = (const float*)d_in[0];
    const float* w0   = (const float*)d_in[1];
    const float* b0   = (const float*)d_in[2];
    const float* k3_0 = (const float*)d_in[3];
    const float* k5_0 = (const float*)d_in[4];
    const float* k7_0 = (const float*)d_in[5];
    const float* g0   = (const float*)d_in[6];
    const float* be0  = (const float*)d_in[7];
    const float* mu0  = (const float*)d_in[8];
    const float* v0   = (const float*)d_in[9];
    const float* w1   = (const float*)d_in[10];
    const float* b1   = (const float*)d_in[11];
    const float* k3_1 = (const float*)d_in[12];
    const float* k5_1 = (const float*)d_in[13];
    const float* k7_1 = (const float*)d_in[14];
    const float* g1   = (const float*)d_in[15];
    const float* be1  = (const float*)d_in[16];
    const float* mu1  = (const float*)d_in[17];
    const float* v1   = (const float*)d_in[18];

    float* ext0          = (float*)d_ws;                       // 2,097,152 f32
    unsigned short* zb   = (unsigned short*)(ext0 + 2097152);  // 33,423,360 bf16
    unsigned short* e1   = zb + 33423360;                      // 1,310,720 bf16

    tc_reduce0<<<16*64, 256, 0, stream>>>(x, ext0);
    tc_layer0 <<<816*8, 256, 0, stream>>>(x, ext0, w0, b0, k3_0, k5_0, k7_0,
                                          g0, be0, mu0, v0, zb);
    tc_reduce1<<<16*32, 320, 0, stream>>>(zb, e1);
    tc_layer1 <<<848*8, 256, 0, stream>>>(zb, e1, w1, b1, k3_1, k5_1, k7_1,
                                          g1, be1, mu1, v1, (float*)d_out);
    tc_shuffle<<<16*16*53, 256, 0, stream>>>((float*)d_out);
}

// Round 4
// 311.454 us; speedup vs baseline: 5.8105x; 1.1476x over previous
//
#include <hip/hip_runtime.h>
#include <hip/hip_bf16.h>

#define EPSBN 1e-3f

typedef __attribute__((ext_vector_type(8))) short bf16x8;
typedef __attribute__((ext_vector_type(8))) unsigned short ushort8;
typedef __attribute__((ext_vector_type(4))) float f32x4;

// ---------------------------------------------------------------------------
//   x    : (16, 64, 49, 1024) f32
//   ext0 : (16, 64, 2, 1024)  f32    [slot 0: max over s, slot 1: mean]
//   z0g  : (16, 32, 51, 1280) bf16   GROUP-MAJOR: ch = g0*160 + (p*32+n)
//   ext1 : (16, 32, 2, 1280)  bf16
//   W0t  : bf16 [8 g][160 n][128 k]          (pre-transposed by tc_prep)
//   W1t  : bf16 [8 g][200 n][160 k-permuted] (kref = (k%20)*8 + k/20)
//   out  : (16, 16, 53, 1600) f32    group-major (g1*200 + p*40+n), then
//                                    shuffled in place to ref order pq*8+g1.
// ---------------------------------------------------------------------------

__device__ __forceinline__ float bf2f(unsigned short u) {
    union { unsigned int i; float f; } c; c.i = (unsigned int)u << 16; return c.f;
}
__device__ __forceinline__ unsigned short f2bf(float f) {
    union { float f; unsigned int i; } c; c.f = f;
    unsigned int r = c.i + 0x7FFF + ((c.i >> 16) & 1);   // RNE
    return (unsigned short)(r >> 16);
}

// ---------------------------------------------------------------------------
// One-shot weight transpose+convert.  419840 total elements.
// ---------------------------------------------------------------------------
__global__ __launch_bounds__(256) void tc_prep(const float* __restrict__ w0,
                                               const float* __restrict__ w1,
                                               unsigned short* __restrict__ W0t,
                                               unsigned short* __restrict__ W1t) {
    const int idx = blockIdx.x * 256 + threadIdx.x;
    if (idx < 163840) {                         // 8*160*128
        const int g   = idx / 20480;
        const int rem = idx - g*20480;
        const int n   = rem >> 7;
        const int k   = rem & 127;
        const int p   = n >> 5, nn = n & 31;
        W0t[idx] = f2bf(w0[(((size_t)p*8 + g)*128 + k)*32 + nn]);
    } else if (idx < 163840 + 256000) {         // 8*200*160
        const int i2  = idx - 163840;
        const int g   = i2 / 32000;
        const int rem = i2 - g*32000;
        const int n   = rem / 160;
        const int k   = rem - n*160;
        const int kref = (k % 20)*8 + k/20;
        const int p   = n / 40, nn = n - p*40;
        W1t[i2] = f2bf(w1[(((size_t)p*8 + g)*160 + kref)*40 + nn]);
    }
}

__global__ __launch_bounds__(256) void tc_reduce0(const float* __restrict__ x,
                                                  float* __restrict__ ext) {
    const int bt = blockIdx.x;              // b*64+t
    const int c  = threadIdx.x * 4;
    const float4* src = reinterpret_cast<const float4*>(x + (size_t)bt * 49 * 1024 + c);
    float4 v = src[0];
    float mx0 = v.x, mx1 = v.y, mx2 = v.z, mx3 = v.w;
    float sm0 = v.x, sm1 = v.y, sm2 = v.z, sm3 = v.w;
    for (int s = 1; s < 49; ++s) {
        float4 u = src[(size_t)s * 256];
        mx0 = fmaxf(mx0, u.x); sm0 += u.x;
        mx1 = fmaxf(mx1, u.y); sm1 += u.y;
        mx2 = fmaxf(mx2, u.z); sm2 += u.z;
        mx3 = fmaxf(mx3, u.w); sm3 += u.w;
    }
    const float inv = 1.0f / 49.0f;
    float* d = ext + (size_t)bt * 2048 + c;
    *reinterpret_cast<float4*>(d)        = make_float4(mx0, mx1, mx2, mx3);
    *reinterpret_cast<float4*>(d + 1024) = make_float4(sm0*inv, sm1*inv, sm2*inv, sm3*inv);
}

__global__ __launch_bounds__(320) void tc_reduce1(const unsigned short* __restrict__ zb,
                                                  unsigned short* __restrict__ ext) {
    const int bt = blockIdx.x;              // b*32+t
    const int c  = threadIdx.x * 4;         // 0..1276
    const unsigned short* src = zb + (size_t)bt * 51 * 1280 + c;
    ushort4 u = *reinterpret_cast<const ushort4*>(src);
    float v0 = bf2f(u.x), v1 = bf2f(u.y), v2 = bf2f(u.z), v3 = bf2f(u.w);
    float mx0 = v0, mx1 = v1, mx2 = v2, mx3 = v3;
    float sm0 = v0, sm1 = v1, sm2 = v2, sm3 = v3;
    for (int s = 1; s < 51; ++s) {
        ushort4 w = *reinterpret_cast<const ushort4*>(src + (size_t)s * 1280);
        v0 = bf2f(w.x); v1 = bf2f(w.y); v2 = bf2f(w.z); v3 = bf2f(w.w);
        mx0 = fmaxf(mx0, v0); sm0 += v0;
        mx1 = fmaxf(mx1, v1); sm1 += v1;
        mx2 = fmaxf(mx2, v2); sm2 += v2;
        mx3 = fmaxf(mx3, v3); sm3 += v3;
    }
    const float inv = 1.0f / 51.0f;
    unsigned short* d = ext + (size_t)bt * 2560 + c;
    ushort4 o;
    o.x = f2bf(mx0); o.y = f2bf(mx1); o.z = f2bf(mx2); o.w = f2bf(mx3);
    *reinterpret_cast<ushort4*>(d) = o;
    o.x = f2bf(sm0*inv); o.y = f2bf(sm1*inv); o.z = f2bf(sm2*inv); o.w = f2bf(sm3*inv);
    *reinterpret_cast<ushort4*>(d + 1280) = o;
}

// ---------------------------------------------------------------------------
// Layer 0: block (b, s<51, g<8).  MFMA: D = W^T x A^T -> Yt[n][t].
// W staged from pre-transposed W0t in two 64-k chunks (pure ushort8 copies).
// ---------------------------------------------------------------------------
__global__ __launch_bounds__(256, 3) void tc_layer0(
    const float* __restrict__ x, const float* __restrict__ ext,
    const unsigned short* __restrict__ W0t, const float* __restrict__ bias,
    const float* __restrict__ k3, const float* __restrict__ k5,
    const float* __restrict__ k7,
    const float* __restrict__ gam, const float* __restrict__ bet,
    const float* __restrict__ mu, const float* __restrict__ var,
    unsigned short* __restrict__ zb)
{
    const int tid = threadIdx.x;
    const int g  = blockIdx.x / 816;
    const int bs = blockIdx.x % 816;
    const int s  = bs % 51;
    const int b  = bs / 51;

    __shared__ __align__(16) float ldsf[10880];         // 43.5 KB
    unsigned short* AtU = (unsigned short*)ldsf;        // 64 x 136 bf16 (17.4 KB)
    unsigned short* WtU = AtU + 64*136;                 // 160 x 72 bf16 (23.0 KB)
    float* Yt = ldsf;                                   // 160 x 68 f32 (overlay)

    // ---- stage At (64 t x 128 k) f32 -> bf16 ----
    #pragma unroll
    for (int it = 0; it < 8; ++it) {
        const int fid = tid + it*256;           // < 2048
        const int t  = fid >> 5;
        const int k4 = (fid & 31) * 4;
        const float* src = (s < 49)
            ? x   + ((size_t)(b*64 + t)*49 + s) * 1024 + g*128 + k4
            : ext + ((size_t)(b*64 + t)*2 + (s-49)) * 1024 + g*128 + k4;
        const float4 v = *reinterpret_cast<const float4*>(src);
        ushort4 u;
        u.x = f2bf(v.x); u.y = f2bf(v.y); u.z = f2bf(v.z); u.w = f2bf(v.w);
        *reinterpret_cast<ushort4*>(&AtU[t*136 + k4]) = u;
    }

    const int lane = tid & 63;
    const int wid  = tid >> 6;              // wave = t-tile (0..3)
    const int fr   = lane & 15;
    const int kb   = lane >> 4;

    f32x4 zero = {0.f, 0.f, 0.f, 0.f};
    f32x4 acc[10];
    #pragma unroll
    for (int i = 0; i < 10; ++i) acc[i] = zero;

    for (int kc = 0; kc < 2; ++kc) {
        __syncthreads();
        // stage Wt chunk: 160 n x 64 k, contiguous ushort8 copies
        #pragma unroll
        for (int it = 0; it < 5; ++it) {
            const int gi = tid + it*256;        // < 1280
            const int n    = gi >> 3;
            const int part = gi & 7;
            *reinterpret_cast<ushort8*>(&WtU[n*72 + part*8]) =
                *reinterpret_cast<const ushort8*>(
                    &W0t[((size_t)g*160 + n)*128 + kc*64 + part*8]);
        }
        __syncthreads();
        #pragma unroll
        for (int ks = 0; ks < 2; ++ks) {
            const bf16x8 bfrag = *reinterpret_cast<const bf16x8*>(
                &AtU[(wid*16 + fr)*136 + kc*64 + ks*32 + kb*8]);
            #pragma unroll
            for (int nt = 0; nt < 10; ++nt) {
                const bf16x8 afrag = *reinterpret_cast<const bf16x8*>(
                    &WtU[(nt*16 + fr)*72 + ks*32 + kb*8]);
                acc[nt] = __builtin_amdgcn_mfma_f32_16x16x32_bf16(afrag, bfrag, acc[nt], 0, 0, 0);
            }
        }
    }
    __syncthreads();
    // D: row(n) = nt*16 + kb*4 + r, col(t) = wid*16 + fr
    #pragma unroll
    for (int nt = 0; nt < 10; ++nt)
        #pragma unroll
        for (int r = 0; r < 4; ++r)
            Yt[(nt*16 + kb*4 + r)*68 + wid*16 + fr] = acc[nt][r];
    __syncthreads();

    // ---- epilogue: one thread per channel, contiguous-t register sweep ----
    if (tid < 160) {
        const int ch = tid;
        const int p  = ch >> 5, n = ch & 31;
        const int pi = (p*8 + g)*32 + n;
        const float bsv = bias[pi];
        const float sc  = gam[pi]*rsqrtf(var[pi]+EPSBN);
        const float sh  = bet[pi] - mu[pi]*sc;
        float yv[64];
        const float4* yr = reinterpret_cast<const float4*>(&Yt[ch*68]);
        #pragma unroll
        for (int i = 0; i < 16; ++i) {
            const float4 v = yr[i];
            yv[4*i+0] = v.x + bsv; yv[4*i+1] = v.y + bsv;
            yv[4*i+2] = v.z + bsv; yv[4*i+3] = v.w + bsv;
        }
        unsigned short* zp = zb + ((size_t)(b*32)*51 + s)*1280 + g*160 + ch;
        if (p == 0) {
            #pragma unroll
            for (int tq = 0; tq < 32; ++tq) {
                const float r = fmaxf(fmaxf(fmaf(yv[2*tq],sc,sh), fmaf(yv[2*tq+1],sc,sh)), 0.f);
                zp[(size_t)tq*65280] = f2bf(r);
            }
        } else if (p == 1) {
            const float w0_ = k3[(g*32+n)*3+0], w1_ = k3[(g*32+n)*3+1], w2_ = k3[(g*32+n)*3+2];
            #pragma unroll
            for (int tq = 0; tq < 32; ++tq) {
                float a = yv[2*tq]*w1_;
                if (tq > 0) a = fmaf(yv[2*tq-1], w0_, a);
                a = fmaf(yv[2*tq+1], w2_, a);
                float c2 = fmaf(yv[2*tq], w0_, yv[2*tq+1]*w1_);
                if (tq < 31) c2 = fmaf(yv[2*tq+2], w2_, c2);
                const float r = fmaxf(fmaxf(fmaf(a,sc,sh), fmaf(c2,sc,sh)), 0.f);
                zp[(size_t)tq*65280] = f2bf(r);
            }
        } else if (p == 2) {
            float wk[5];
            #pragma unroll
            for (int j = 0; j < 5; ++j) wk[j] = k5[(g*32+n)*5+j];
            #pragma unroll
            for (int tq = 0; tq < 32; ++tq) {
                float vv[2];
                #pragma unroll
                for (int q = 0; q < 2; ++q) {
                    const int t = 2*tq + q;
                    float v = 0.f;
                    #pragma unroll
                    for (int j = 0; j < 5; ++j) {
                        const int ttp = t + j - 2;
                        if (ttp >= 0 && ttp < 64) v = fmaf(yv[ttp], wk[j], v);
                    }
                    vv[q] = v;
                }
                const float r = fmaxf(fmaxf(fmaf(vv[0],sc,sh), fmaf(vv[1],sc,sh)), 0.f);
                zp[(size_t)tq*65280] = f2bf(r);
            }
        } else if (p == 3) {
            float wk[7];
            #pragma unroll
            for (int j = 0; j < 7; ++j) wk[j] = k7[(g*32+n)*7+j];
            #pragma unroll
            for (int tq = 0; tq < 32; ++tq) {
                float vv[2];
                #pragma unroll
                for (int q = 0; q < 2; ++q) {
                    const int t = 2*tq + q;
                    float v = 0.f;
                    #pragma unroll
                    for (int j = 0; j < 7; ++j) {
                        const int ttp = t + j - 3;
                        if (ttp >= 0 && ttp < 64) v = fmaf(yv[ttp], wk[j], v);
                    }
                    vv[q] = v;
                }
                const float r = fmaxf(fmaxf(fmaf(vv[0],sc,sh), fmaf(vv[1],sc,sh)), 0.f);
                zp[(size_t)tq*65280] = f2bf(r);
            }
        } else {
            #pragma unroll
            for (int tq = 0; tq < 32; ++tq) {
                const float v0 = fmaxf(yv[2*tq], yv[2*tq+1]);
                const float v1 = fmaxf(yv[2*tq+1], yv[(2*tq+2 < 64) ? 2*tq+2 : 63]);
                const float r = fmaxf(fmaxf(fmaf(v0,sc,sh), fmaf(v1,sc,sh)), 0.f);
                zp[(size_t)tq*65280] = f2bf(r);
            }
        }
    }
}

// ---------------------------------------------------------------------------
// Layer 1: block (b, s<53, g<8).  A gathered from z0g; W staged from W1t
// (k-permutation already baked in).  Writes d_out group-major.
// ---------------------------------------------------------------------------
__global__ __launch_bounds__(256, 5) void tc_layer1(
    const unsigned short* __restrict__ zbi, const unsigned short* __restrict__ ext,
    const unsigned short* __restrict__ W1t, const float* __restrict__ bias,
    const float* __restrict__ k3, const float* __restrict__ k5,
    const float* __restrict__ k7,
    const float* __restrict__ gam, const float* __restrict__ bet,
    const float* __restrict__ mu, const float* __restrict__ var,
    float* __restrict__ out)
{
    const int tid = threadIdx.x;
    const int g  = blockIdx.x / 848;        // same-(b,s) blocks = same XCD
    const int bs = blockIdx.x % 848;
    const int s  = bs % 53;
    const int b  = bs / 53;

    __shared__ __align__(16) float ldsf[7200];          // 28.8 KB
    unsigned short* AtU = (unsigned short*)ldsf;        // 32 x 168 bf16 (10.75 KB)
    unsigned short* WtU = AtU + 32*168;                 // 200 x 40 bf16 (16.0 KB)
    float* Yt = ldsf;                                   // 200 x 36 f32 (overlay)

    // ---- gather At (32 t x 160 k, z0g k-order) bf16 ----
    #pragma unroll
    for (int it = 0; it < 5; ++it) {
        const int fid = tid + it*256;           // < 1280
        const int t   = fid / 40;
        const int seg = fid - t*40;
        const int gg  = seg / 5, q = seg - gg*5;
        const int ch  = gg*160 + g*20 + q*4;
        const unsigned short* src = (s < 51)
            ? zbi + ((size_t)(b*32 + t)*51 + s) * 1280 + ch
            : ext + ((size_t)(b*32 + t)*2 + (s-51)) * 1280 + ch;
        *reinterpret_cast<ushort4*>(&AtU[t*168 + seg*4]) =
            *reinterpret_cast<const ushort4*>(src);
    }

    const int lane = tid & 63;
    const int wid  = tid >> 6;
    const int tt_  = wid & 1;               // t-tile
    const int nh   = wid >> 1;              // n-half
    const int nbase = nh * 7;               // nh0: nt 0..6, nh1: nt 7..12
    const int fr   = lane & 15;
    const int kb   = lane >> 4;

    f32x4 zero = {0.f, 0.f, 0.f, 0.f};
    f32x4 acc[7];
    #pragma unroll
    for (int i = 0; i < 7; ++i) acc[i] = zero;

    for (int kc = 0; kc < 5; ++kc) {
        __syncthreads();
        // stage Wt chunk: 200 n x 32 k, contiguous ushort8 copies
        #pragma unroll
        for (int it = 0; it < 4; ++it) {
            const int gi = tid + it*256;        // < 800
            if (gi < 800) {
                const int n    = gi >> 2;
                const int part = gi & 3;
                *reinterpret_cast<ushort8*>(&WtU[n*40 + part*8]) =
                    *reinterpret_cast<const ushort8*>(
                        &W1t[((size_t)g*200 + n)*160 + kc*32 + part*8]);
            }
        }
        __syncthreads();
        const bf16x8 bfrag = *reinterpret_cast<const bf16x8*>(
            &AtU[(tt_*16 + fr)*168 + kc*32 + kb*8]);
        #pragma unroll
        for (int i = 0; i < 7; ++i) {
            const int nt = nbase + i;
            if (nt < 13) {
                const bf16x8 afrag = *reinterpret_cast<const bf16x8*>(
                    &WtU[(nt*16 + fr)*40 + kb*8]);
                acc[i] = __builtin_amdgcn_mfma_f32_16x16x32_bf16(afrag, bfrag, acc[i], 0, 0, 0);
            }
        }
    }
    __syncthreads();
    #pragma unroll
    for (int i = 0; i < 7; ++i) {
        const int nt = nbase + i;
        if (nt < 13) {
            #pragma unroll
            for (int r = 0; r < 4; ++r) {
                const int row = nt*16 + kb*4 + r;
                if (row < 200) Yt[row*36 + tt_*16 + fr] = acc[i][r];
            }
        }
    }
    __syncthreads();

    if (tid < 200) {
        const int ch = tid;
        const int p  = ch / 40, n = ch - p*40;
        const int pi = (p*8 + g)*40 + n;
        const float bsv = bias[pi];
        const float sc  = gam[pi]*rsqrtf(var[pi]+EPSBN);
        const float sh  = bet[pi] - mu[pi]*sc;
        float yv[32];
        const float4* yr = reinterpret_cast<const float4*>(&Yt[ch*36]);
        #pragma unroll
        for (int i = 0; i < 8; ++i) {
            const float4 v = yr[i];
            yv[4*i+0] = v.x + bsv; yv[4*i+1] = v.y + bsv;
            yv[4*i+2] = v.z + bsv; yv[4*i+3] = v.w + bsv;
        }
        float* op = out + ((size_t)(b*16)*53 + s)*1600 + g*200 + ch;
        if (p == 0) {
            #pragma unroll
            for (int tq = 0; tq < 16; ++tq)
                op[(size_t)tq*84800] =
                    fmaxf(fmaxf(fmaf(yv[2*tq],sc,sh), fmaf(yv[2*tq+1],sc,sh)), 0.f);
        } else if (p == 1) {
            const float w0_ = k3[(g*40+n)*3+0], w1_ = k3[(g*40+n)*3+1], w2_ = k3[(g*40+n)*3+2];
            #pragma unroll
            for (int tq = 0; tq < 16; ++tq) {
                float a = yv[2*tq]*w1_;
                if (tq > 0) a = fmaf(yv[2*tq-1], w0_, a);
                a = fmaf(yv[2*tq+1], w2_, a);
                float c2 = fmaf(yv[2*tq], w0_, yv[2*tq+1]*w1_);
                if (tq < 15) c2 = fmaf(yv[2*tq+2], w2_, c2);
                op[(size_t)tq*84800] = fmaxf(fmaxf(fmaf(a,sc,sh), fmaf(c2,sc,sh)), 0.f);
            }
        } else if (p == 2) {
            float wk[5];
            #pragma unroll
            for (int j = 0; j < 5; ++j) wk[j] = k5[(g*40+n)*5+j];
            #pragma unroll
            for (int tq = 0; tq < 16; ++tq) {
                float vv[2];
                #pragma unroll
                for (int q = 0; q < 2; ++q) {
                    const int t = 2*tq + q;
                    float v = 0.f;
                    #pragma unroll
                    for (int j = 0; j < 5; ++j) {
                        const int ttp = t + j - 2;
                        if (ttp >= 0 && ttp < 32) v = fmaf(yv[ttp], wk[j], v);
                    }
                    vv[q] = v;
                }
                op[(size_t)tq*84800] = fmaxf(fmaxf(fmaf(vv[0],sc,sh), fmaf(vv[1],sc,sh)), 0.f);
            }
        } else if (p == 3) {
            float wk[7];
            #pragma unroll
            for (int j = 0; j < 7; ++j) wk[j] = k7[(g*40+n)*7+j];
            #pragma unroll
            for (int tq = 0; tq < 16; ++tq) {
                float vv[2];
                #pragma unroll
                for (int q = 0; q < 2; ++q) {
                    const int t = 2*tq + q;
                    float v = 0.f;
                    #pragma unroll
                    for (int j = 0; j < 7; ++j) {
                        const int ttp = t + j - 3;
                        if (ttp >= 0 && ttp < 32) v = fmaf(yv[ttp], wk[j], v);
                    }
                    vv[q] = v;
                }
                op[(size_t)tq*84800] = fmaxf(fmaxf(fmaf(vv[0],sc,sh), fmaf(vv[1],sc,sh)), 0.f);
            }
        } else {
            #pragma unroll
            for (int tq = 0; tq < 16; ++tq) {
                const float v0 = fmaxf(yv[2*tq], yv[2*tq+1]);
                const float v1 = fmaxf(yv[2*tq+1], yv[(2*tq+2 < 32) ? 2*tq+2 : 31]);
                op[(size_t)tq*84800] = fmaxf(fmaxf(fmaf(v0,sc,sh), fmaf(v1,sc,sh)), 0.f);
            }
        }
    }
}

// ---------------------------------------------------------------------------
// In-place channel shuffle of d_out rows: group-major (g*200+pq) -> pq*8+g
// ---------------------------------------------------------------------------
__global__ __launch_bounds__(256) void tc_shuffle(float* __restrict__ o) {
    __shared__ float row[1600];
    const size_t base = (size_t)blockIdx.x * 1600;
    const int tid = threadIdx.x;
    #pragma unroll
    for (int it = 0; it < 2; ++it) {
        const int f4 = tid + it*256;
        if (f4 < 400)
            *reinterpret_cast<float4*>(&row[f4*4]) =
                *reinterpret_cast<const float4*>(&o[base + (size_t)f4*4]);
    }
    __syncthreads();
    #pragma unroll
    for (int it = 0; it < 2; ++it) {
        const int f4 = tid + it*256;
        if (f4 < 400) {
            const int c = f4*4;
            float4 v;
            v.x = row[((c  ) & 7)*200 + ((c  ) >> 3)];
            v.y = row[((c+1) & 7)*200 + ((c+1) >> 3)];
            v.z = row[((c+2) & 7)*200 + ((c+2) >> 3)];
            v.w = row[((c+3) & 7)*200 + ((c+3) >> 3)];
            *reinterpret_cast<float4*>(&o[base + (size_t)c]) = v;
        }
    }
}

extern "C" void kernel_launch(void* const* d_in, const int* in_sizes, int n_in,
                              void* d_out, int out_size, void* d_ws, size_t ws_size,
                              hipStream_t stream) {
    const float* x    = (const float*)d_in[0];
    const float* w0   = (const float*)d_in[1];
    const float* b0   = (const float*)d_in[2];
    const float* k3_0 = (const float*)d_in[3];
    const float* k5_0 = (const float*)d_in[4];
    const float* k7_0 = (const float*)d_in[5];
    const float* g0   = (const float*)d_in[6];
    const float* be0  = (const float*)d_in[7];
    const float* mu0  = (const float*)d_in[8];
    const float* v0   = (const float*)d_in[9];
    const float* w1   = (const float*)d_in[10];
    const float* b1   = (const float*)d_in[11];
    const float* k3_1 = (const float*)d_in[12];
    const float* k5_1 = (const float*)d_in[13];
    const float* k7_1 = (const float*)d_in[14];
    const float* g1   = (const float*)d_in[15];
    const float* be1  = (const float*)d_in[16];
    const float* mu1  = (const float*)d_in[17];
    const float* v1   = (const float*)d_in[18];

    float* ext0          = (float*)d_ws;                       // 2,097,152 f32
    unsigned short* zb   = (unsigned short*)(ext0 + 2097152);  // 33,423,360 bf16
    unsigned short* e1   = zb + 33423360;                      // 1,310,720 bf16
    unsigned short* W0t  = e1 + 1310720;                       // 163,840 bf16
    unsigned short* W1t  = W0t + 163840;                       // 256,000 bf16

    tc_prep   <<<1640, 256, 0, stream>>>(w0, w1, W0t, W1t);
    tc_reduce0<<<16*64, 256, 0, stream>>>(x, ext0);
    tc_layer0 <<<816*8, 256, 0, stream>>>(x, ext0, W0t, b0, k3_0, k5_0, k7_0,
                                          g0, be0, mu0, v0, zb);
    tc_reduce1<<<16*32, 320, 0, stream>>>(zb, e1);
    tc_layer1 <<<848*8, 256, 0, stream>>>(zb, e1, W1t, b1, k3_1, k5_1, k7_1,
                                          g1, be1, mu1, v1, (float*)d_out);
    tc_shuffle<<<16*16*53, 256, 0, stream>>>((float*)d_out);
}

// Round 5
// 286.602 us; speedup vs baseline: 6.3144x; 1.0867x over previous
//
#include <hip/hip_runtime.h>
#include <hip/hip_bf16.h>

#define EPSBN 1e-3f

typedef __attribute__((ext_vector_type(8))) short bf16x8;
typedef __attribute__((ext_vector_type(8))) unsigned short ushort8;
typedef __attribute__((ext_vector_type(4))) float f32x4;

// ---------------------------------------------------------------------------
//   x    : (16, 64, 49, 1024) f32
//   xb   : (16, 51, 64, 1024) bf16   [s<49: copy of x; s=49: max; s=50: mean]
//   extb : (16, 2, 64, 1024)  bf16   fallback when ws too small for xb
//   zb2  : (16, 32, 53, 1280) bf16   GROUP-MAJOR ch = g0*160 + (p*32+n);
//                                    s<51 by layer0, s=51,52 by reduce1
//   W0t  : bf16 [8 g][160 n][128 k]
//   W1t  : bf16 [8 g][200 n][160 k-permuted] (kref = (k%20)*8 + k/20)
//   out  : (16, 16, 53, 1600) f32    group-major, shuffled in place at end
// ---------------------------------------------------------------------------

__device__ __forceinline__ float bf2f(unsigned short u) {
    union { unsigned int i; float f; } c; c.i = (unsigned int)u << 16; return c.f;
}
__device__ __forceinline__ unsigned short f2bf(float f) {
    union { float f; unsigned int i; } c; c.f = f;
    unsigned int r = c.i + 0x7FFF + ((c.i >> 16) & 1);   // RNE
    return (unsigned short)(r >> 16);
}

// ---------------------------------------------------------------------------
__global__ __launch_bounds__(256) void tc_prep(const float* __restrict__ w0,
                                               const float* __restrict__ w1,
                                               unsigned short* __restrict__ W0t,
                                               unsigned short* __restrict__ W1t) {
    const int idx = blockIdx.x * 256 + threadIdx.x;
    if (idx < 163840) {                         // 8*160*128
        const int g   = idx / 20480;
        const int rem = idx - g*20480;
        const int n   = rem >> 7;
        const int k   = rem & 127;
        const int p   = n >> 5, nn = n & 31;
        W0t[idx] = f2bf(w0[(((size_t)p*8 + g)*128 + k)*32 + nn]);
    } else if (idx < 163840 + 256000) {         // 8*200*160
        const int i2  = idx - 163840;
        const int g   = i2 / 32000;
        const int rem = i2 - g*32000;
        const int n   = rem / 160;
        const int k   = rem - n*160;
        const int kref = (k % 20)*8 + k/20;
        const int p   = n / 40, nn = n - p*40;
        W1t[i2] = f2bf(w1[(((size_t)p*8 + g)*160 + kref)*40 + nn]);
    }
}

// ---------------------------------------------------------------------------
__global__ __launch_bounds__(256) void tc_reduce0(const float* __restrict__ x,
                                                  unsigned short* __restrict__ xb,
                                                  unsigned short* __restrict__ extb,
                                                  const int big) {
    const int bt = blockIdx.x;              // b*64+t
    const int b  = bt >> 6, t = bt & 63;
    const int c  = threadIdx.x * 4;
    const float4* src = reinterpret_cast<const float4*>(x + (size_t)bt * 49 * 1024 + c);
    float4 v = src[0];
    float mx0 = v.x, mx1 = v.y, mx2 = v.z, mx3 = v.w;
    float sm0 = v.x, sm1 = v.y, sm2 = v.z, sm3 = v.w;
    if (big) {
        ushort4 o; o.x=f2bf(v.x); o.y=f2bf(v.y); o.z=f2bf(v.z); o.w=f2bf(v.w);
        *reinterpret_cast<ushort4*>(&xb[((size_t)(b*51)*64 + t)*1024 + c]) = o;
    }
    for (int s = 1; s < 49; ++s) {
        float4 u = src[(size_t)s * 256];
        mx0 = fmaxf(mx0, u.x); sm0 += u.x;
        mx1 = fmaxf(mx1, u.y); sm1 += u.y;
        mx2 = fmaxf(mx2, u.z); sm2 += u.z;
        mx3 = fmaxf(mx3, u.w); sm3 += u.w;
        if (big) {
            ushort4 o; o.x=f2bf(u.x); o.y=f2bf(u.y); o.z=f2bf(u.z); o.w=f2bf(u.w);
            *reinterpret_cast<ushort4*>(&xb[((size_t)(b*51 + s)*64 + t)*1024 + c]) = o;
        }
    }
    const float inv = 1.0f / 49.0f;
    ushort4 omx, omn;
    omx.x=f2bf(mx0); omx.y=f2bf(mx1); omx.z=f2bf(mx2); omx.w=f2bf(mx3);
    omn.x=f2bf(sm0*inv); omn.y=f2bf(sm1*inv); omn.z=f2bf(sm2*inv); omn.w=f2bf(sm3*inv);
    if (big) {
        *reinterpret_cast<ushort4*>(&xb[((size_t)(b*51 + 49)*64 + t)*1024 + c]) = omx;
        *reinterpret_cast<ushort4*>(&xb[((size_t)(b*51 + 50)*64 + t)*1024 + c]) = omn;
    } else {
        *reinterpret_cast<ushort4*>(&extb[((size_t)(b*2 + 0)*64 + t)*1024 + c]) = omx;
        *reinterpret_cast<ushort4*>(&extb[((size_t)(b*2 + 1)*64 + t)*1024 + c]) = omn;
    }
}

// ---------------------------------------------------------------------------
// Layer 0: block (b, s<51, g<8).  MFMA D = W^T x A^T -> Yt[n][t] (bf16 in LDS).
// ---------------------------------------------------------------------------
template<int BIG>
__global__ __launch_bounds__(256, 5) void tc_layer0(
    const float* __restrict__ x, const unsigned short* __restrict__ xb,
    const unsigned short* __restrict__ extb,
    const unsigned short* __restrict__ W0t, const float* __restrict__ bias,
    const float* __restrict__ k3, const float* __restrict__ k5,
    const float* __restrict__ k7,
    const float* __restrict__ gam, const float* __restrict__ bet,
    const float* __restrict__ mu, const float* __restrict__ var,
    unsigned short* __restrict__ zb)
{
    const int tid = threadIdx.x;
    const int g  = blockIdx.x / 816;
    const int bs = blockIdx.x % 816;
    const int s  = bs % 51;
    const int b  = bs / 51;

    __shared__ __align__(16) unsigned short lds[15104];     // 30.2 KB
    unsigned short* AtU = lds;                              // 64 x 136 bf16
    unsigned short* WtU = lds + 64*136;                     // 160 x 40 bf16 (32-k chunk)
    unsigned short* Ytb = lds;                              // 160 x 72 bf16 (overlay)

    // ---- stage At (64 t x 128 k) bf16 ----
    #pragma unroll
    for (int it = 0; it < 4; ++it) {
        const int fid = tid + it*256;           // < 1024
        const int row = fid >> 4;
        const int ch8 = (fid & 15) * 8;
        ushort8 u;
        if (BIG) {
            u = *reinterpret_cast<const ushort8*>(
                &xb[((size_t)(b*51 + s)*64 + row)*1024 + g*128 + ch8]);
        } else if (s < 49) {
            const float* sp = x + ((size_t)(b*64 + row)*49 + s)*1024 + g*128 + ch8;
            const float4 f0 = *reinterpret_cast<const float4*>(sp);
            const float4 f1 = *reinterpret_cast<const float4*>(sp + 4);
            u[0]=f2bf(f0.x); u[1]=f2bf(f0.y); u[2]=f2bf(f0.z); u[3]=f2bf(f0.w);
            u[4]=f2bf(f1.x); u[5]=f2bf(f1.y); u[6]=f2bf(f1.z); u[7]=f2bf(f1.w);
        } else {
            u = *reinterpret_cast<const ushort8*>(
                &extb[((size_t)(b*2 + (s-49))*64 + row)*1024 + g*128 + ch8]);
        }
        *reinterpret_cast<ushort8*>(&AtU[row*136 + ch8]) = u;
    }

    const int lane = tid & 63;
    const int wid  = tid >> 6;              // t-tile 0..3
    const int fr   = lane & 15;
    const int kb   = lane >> 4;

    f32x4 zero = {0.f, 0.f, 0.f, 0.f};
    f32x4 acc[10];
    #pragma unroll
    for (int i = 0; i < 10; ++i) acc[i] = zero;

    for (int kc = 0; kc < 4; ++kc) {
        __syncthreads();
        #pragma unroll
        for (int it = 0; it < 3; ++it) {        // stage 160 n x 32 k
            const int gi = tid + it*256;        // < 640
            if (gi < 640) {
                const int n = gi >> 2, part = (gi & 3) * 8;
                *reinterpret_cast<ushort8*>(&WtU[n*40 + part]) =
                    *reinterpret_cast<const ushort8*>(
                        &W0t[((size_t)g*160 + n)*128 + kc*32 + part]);
            }
        }
        __syncthreads();
        const bf16x8 bfrag = *reinterpret_cast<const bf16x8*>(
            &AtU[(wid*16 + fr)*136 + kc*32 + kb*8]);
        #pragma unroll
        for (int nt = 0; nt < 10; ++nt) {
            const bf16x8 afrag = *reinterpret_cast<const bf16x8*>(
                &WtU[(nt*16 + fr)*40 + kb*8]);
            acc[nt] = __builtin_amdgcn_mfma_f32_16x16x32_bf16(afrag, bfrag, acc[nt], 0, 0, 0);
        }
    }
    __syncthreads();
    // D: row(n) = nt*16 + kb*4 + r, col(t) = wid*16 + fr
    #pragma unroll
    for (int nt = 0; nt < 10; ++nt)
        #pragma unroll
        for (int r = 0; r < 4; ++r)
            Ytb[(nt*16 + kb*4 + r)*72 + wid*16 + fr] = f2bf(acc[nt][r]);
    __syncthreads();

    // ---- epilogue: one thread per channel ----
    if (tid < 160) {
        const int ch = tid;
        const int p  = ch >> 5, n = ch & 31;
        const int pi = (p*8 + g)*32 + n;
        const float bsv = bias[pi];
        const float sc  = gam[pi]*rsqrtf(var[pi]+EPSBN);
        const float sh  = bet[pi] - mu[pi]*sc;
        float yv[64];
        #pragma unroll
        for (int i = 0; i < 8; ++i) {
            const ushort8 u = *reinterpret_cast<const ushort8*>(&Ytb[ch*72 + i*8]);
            #pragma unroll
            for (int j = 0; j < 8; ++j) yv[i*8+j] = bf2f(u[j]) + bsv;
        }
        unsigned short* zp = zb + ((size_t)(b*32)*53 + s)*1280 + g*160 + ch;
        if (p == 0) {
            #pragma unroll
            for (int tq = 0; tq < 32; ++tq) {
                const float r = fmaxf(fmaxf(fmaf(yv[2*tq],sc,sh), fmaf(yv[2*tq+1],sc,sh)), 0.f);
                zp[(size_t)tq*67840] = f2bf(r);
            }
        } else if (p == 1) {
            const float w0_ = k3[(g*32+n)*3+0], w1_ = k3[(g*32+n)*3+1], w2_ = k3[(g*32+n)*3+2];
            #pragma unroll
            for (int tq = 0; tq < 32; ++tq) {
                float a = yv[2*tq]*w1_;
                if (tq > 0) a = fmaf(yv[2*tq-1], w0_, a);
                a = fmaf(yv[2*tq+1], w2_, a);
                float c2 = fmaf(yv[2*tq], w0_, yv[2*tq+1]*w1_);
                if (tq < 31) c2 = fmaf(yv[2*tq+2], w2_, c2);
                const float r = fmaxf(fmaxf(fmaf(a,sc,sh), fmaf(c2,sc,sh)), 0.f);
                zp[(size_t)tq*67840] = f2bf(r);
            }
        } else if (p == 2) {
            float wk[5];
            #pragma unroll
            for (int j = 0; j < 5; ++j) wk[j] = k5[(g*32+n)*5+j];
            #pragma unroll
            for (int tq = 0; tq < 32; ++tq) {
                float vv[2];
                #pragma unroll
                for (int q = 0; q < 2; ++q) {
                    const int t = 2*tq + q;
                    float v = 0.f;
                    #pragma unroll
                    for (int j = 0; j < 5; ++j) {
                        const int ttp = t + j - 2;
                        if (ttp >= 0 && ttp < 64) v = fmaf(yv[ttp], wk[j], v);
                    }
                    vv[q] = v;
                }
                const float r = fmaxf(fmaxf(fmaf(vv[0],sc,sh), fmaf(vv[1],sc,sh)), 0.f);
                zp[(size_t)tq*67840] = f2bf(r);
            }
        } else if (p == 3) {
            float wk[7];
            #pragma unroll
            for (int j = 0; j < 7; ++j) wk[j] = k7[(g*32+n)*7+j];
            #pragma unroll
            for (int tq = 0; tq < 32; ++tq) {
                float vv[2];
                #pragma unroll
                for (int q = 0; q < 2; ++q) {
                    const int t = 2*tq + q;
                    float v = 0.f;
                    #pragma unroll
                    for (int j = 0; j < 7; ++j) {
                        const int ttp = t + j - 3;
                        if (ttp >= 0 && ttp < 64) v = fmaf(yv[ttp], wk[j], v);
                    }
                    vv[q] = v;
                }
                const float r = fmaxf(fmaxf(fmaf(vv[0],sc,sh), fmaf(vv[1],sc,sh)), 0.f);
                zp[(size_t)tq*67840] = f2bf(r);
            }
        } else {
            #pragma unroll
            for (int tq = 0; tq < 32; ++tq) {
                const float v0 = fmaxf(yv[2*tq], yv[2*tq+1]);
                const float v1 = fmaxf(yv[2*tq+1], yv[(2*tq+2 < 64) ? 2*tq+2 : 63]);
                const float r = fmaxf(fmaxf(fmaf(v0,sc,sh), fmaf(v1,sc,sh)), 0.f);
                zp[(size_t)tq*67840] = f2bf(r);
            }
        }
    }
}

// ---------------------------------------------------------------------------
// reduce1: fills zb2 columns s=51 (max) and s=52 (mean) per (b,tq) row.
// ---------------------------------------------------------------------------
__global__ __launch_bounds__(320) void tc_reduce1(unsigned short* __restrict__ zb) {
    const int bt = blockIdx.x;              // b*32+tq
    const int c  = threadIdx.x * 4;         // 0..1276
    unsigned short* base = zb + (size_t)bt * 67840;
    ushort4 u = *reinterpret_cast<const ushort4*>(&base[c]);
    float v0 = bf2f(u.x), v1 = bf2f(u.y), v2 = bf2f(u.z), v3 = bf2f(u.w);
    float mx0 = v0, mx1 = v1, mx2 = v2, mx3 = v3;
    float sm0 = v0, sm1 = v1, sm2 = v2, sm3 = v3;
    for (int s = 1; s < 51; ++s) {
        ushort4 w = *reinterpret_cast<const ushort4*>(&base[(size_t)s*1280 + c]);
        v0 = bf2f(w.x); v1 = bf2f(w.y); v2 = bf2f(w.z); v3 = bf2f(w.w);
        mx0 = fmaxf(mx0, v0); sm0 += v0;
        mx1 = fmaxf(mx1, v1); sm1 += v1;
        mx2 = fmaxf(mx2, v2); sm2 += v2;
        mx3 = fmaxf(mx3, v3); sm3 += v3;
    }
    const float inv = 1.0f / 51.0f;
    ushort4 o;
    o.x = f2bf(mx0); o.y = f2bf(mx1); o.z = f2bf(mx2); o.w = f2bf(mx3);
    *reinterpret_cast<ushort4*>(&base[(size_t)51*1280 + c]) = o;
    o.x = f2bf(sm0*inv); o.y = f2bf(sm1*inv); o.z = f2bf(sm2*inv); o.w = f2bf(sm3*inv);
    *reinterpret_cast<ushort4*>(&base[(size_t)52*1280 + c]) = o;
}

// ---------------------------------------------------------------------------
// Layer 1: block (b, s<53, g<8).  A gathered from zb2 (uniform path).
// ---------------------------------------------------------------------------
__global__ __launch_bounds__(256, 6) void tc_layer1(
    const unsigned short* __restrict__ zbi,
    const unsigned short* __restrict__ W1t, const float* __restrict__ bias,
    const float* __restrict__ k3, const float* __restrict__ k5,
    const float* __restrict__ k7,
    const float* __restrict__ gam, const float* __restrict__ bet,
    const float* __restrict__ mu, const float* __restrict__ var,
    float* __restrict__ out)
{
    const int tid = threadIdx.x;
    const int g  = blockIdx.x / 848;        // same-(b,s) blocks = same XCD
    const int bs = blockIdx.x % 848;
    const int s  = bs % 53;
    const int b  = bs / 53;

    __shared__ __align__(16) unsigned short lds[13376];     // 26.75 KB
    unsigned short* AtU = lds;                              // 32 x 168 bf16
    unsigned short* WtU = lds + 32*168;                     // 200 x 40 bf16 (32-k chunk)
    unsigned short* Ytb = lds;                              // 200 x 40 bf16 (overlay)

    // ---- gather At (32 t x 160 k, z0g k-order) bf16 ----
    #pragma unroll
    for (int it = 0; it < 5; ++it) {
        const int fid = tid + it*256;           // < 1280
        const int t   = fid / 40;
        const int seg = fid - t*40;
        const int gg  = seg / 5, q = seg - gg*5;
        const int ch  = gg*160 + g*20 + q*4;
        const unsigned short* src = zbi + ((size_t)(b*32 + t)*53 + s)*1280 + ch;
        *reinterpret_cast<ushort4*>(&AtU[t*168 + seg*4]) =
            *reinterpret_cast<const ushort4*>(src);
    }

    const int lane = tid & 63;
    const int wid  = tid >> 6;
    const int tt_  = wid & 1;               // t-tile
    const int nh   = wid >> 1;              // n-half
    const int nbase = nh * 7;               // nh0: nt 0..6, nh1: nt 7..12
    const int fr   = lane & 15;
    const int kb   = lane >> 4;

    f32x4 zero = {0.f, 0.f, 0.f, 0.f};
    f32x4 acc[7];
    #pragma unroll
    for (int i = 0; i < 7; ++i) acc[i] = zero;

    for (int kc = 0; kc < 5; ++kc) {
        __syncthreads();
        #pragma unroll
        for (int it = 0; it < 4; ++it) {        // stage 200 n x 32 k
            const int gi = tid + it*256;        // < 800
            if (gi < 800) {
                const int n = gi >> 2, part = (gi & 3) * 8;
                *reinterpret_cast<ushort8*>(&WtU[n*40 + part]) =
                    *reinterpret_cast<const ushort8*>(
                        &W1t[((size_t)g*200 + n)*160 + kc*32 + part]);
            }
        }
        __syncthreads();
        const bf16x8 bfrag = *reinterpret_cast<const bf16x8*>(
            &AtU[(tt_*16 + fr)*168 + kc*32 + kb*8]);
        #pragma unroll
        for (int i = 0; i < 7; ++i) {
            const int nt = nbase + i;
            if (nt < 13) {
                const bf16x8 afrag = *reinterpret_cast<const bf16x8*>(
                    &WtU[(nt*16 + fr)*40 + kb*8]);
                acc[i] = __builtin_amdgcn_mfma_f32_16x16x32_bf16(afrag, bfrag, acc[i], 0, 0, 0);
            }
        }
    }
    __syncthreads();
    #pragma unroll
    for (int i = 0; i < 7; ++i) {
        const int nt = nbase + i;
        if (nt < 13) {
            #pragma unroll
            for (int r = 0; r < 4; ++r) {
                const int row = nt*16 + kb*4 + r;
                if (row < 200) Ytb[row*40 + tt_*16 + fr] = f2bf(acc[i][r]);
            }
        }
    }
    __syncthreads();

    if (tid < 200) {
        const int ch = tid;
        const int p  = ch / 40, n = ch - p*40;
        const int pi = (p*8 + g)*40 + n;
        const float bsv = bias[pi];
        const float sc  = gam[pi]*rsqrtf(var[pi]+EPSBN);
        const float sh  = bet[pi] - mu[pi]*sc;
        float yv[32];
        #pragma unroll
        for (int i = 0; i < 4; ++i) {
            const ushort8 u = *reinterpret_cast<const ushort8*>(&Ytb[ch*40 + i*8]);
            #pragma unroll
            for (int j = 0; j < 8; ++j) yv[i*8+j] = bf2f(u[j]) + bsv;
        }
        float* op = out + ((size_t)(b*16)*53 + s)*1600 + g*200 + ch;
        if (p == 0) {
            #pragma unroll
            for (int tq = 0; tq < 16; ++tq)
                op[(size_t)tq*84800] =
                    fmaxf(fmaxf(fmaf(yv[2*tq],sc,sh), fmaf(yv[2*tq+1],sc,sh)), 0.f);
        } else if (p == 1) {
            const float w0_ = k3[(g*40+n)*3+0], w1_ = k3[(g*40+n)*3+1], w2_ = k3[(g*40+n)*3+2];
            #pragma unroll
            for (int tq = 0; tq < 16; ++tq) {
                float a = yv[2*tq]*w1_;
                if (tq > 0) a = fmaf(yv[2*tq-1], w0_, a);
                a = fmaf(yv[2*tq+1], w2_, a);
                float c2 = fmaf(yv[2*tq], w0_, yv[2*tq+1]*w1_);
                if (tq < 15) c2 = fmaf(yv[2*tq+2], w2_, c2);
                op[(size_t)tq*84800] = fmaxf(fmaxf(fmaf(a,sc,sh), fmaf(c2,sc,sh)), 0.f);
            }
        } else if (p == 2) {
            float wk[5];
            #pragma unroll
            for (int j = 0; j < 5; ++j) wk[j] = k5[(g*40+n)*5+j];
            #pragma unroll
            for (int tq = 0; tq < 16; ++tq) {
                float vv[2];
                #pragma unroll
                for (int q = 0; q < 2; ++q) {
                    const int t = 2*tq + q;
                    float v = 0.f;
                    #pragma unroll
                    for (int j = 0; j < 5; ++j) {
                        const int ttp = t + j - 2;
                        if (ttp >= 0 && ttp < 32) v = fmaf(yv[ttp], wk[j], v);
                    }
                    vv[q] = v;
                }
                op[(size_t)tq*84800] = fmaxf(fmaxf(fmaf(vv[0],sc,sh), fmaf(vv[1],sc,sh)), 0.f);
            }
        } else if (p == 3) {
            float wk[7];
            #pragma unroll
            for (int j = 0; j < 7; ++j) wk[j] = k7[(g*40+n)*7+j];
            #pragma unroll
            for (int tq = 0; tq < 16; ++tq) {
                float vv[2];
                #pragma unroll
                for (int q = 0; q < 2; ++q) {
                    const int t = 2*tq + q;
                    float v = 0.f;
                    #pragma unroll
                    for (int j = 0; j < 7; ++j) {
                        const int ttp = t + j - 3;
                        if (ttp >= 0 && ttp < 32) v = fmaf(yv[ttp], wk[j], v);
                    }
                    vv[q] = v;
                }
                op[(size_t)tq*84800] = fmaxf(fmaxf(fmaf(vv[0],sc,sh), fmaf(vv[1],sc,sh)), 0.f);
            }
        } else {
            #pragma unroll
            for (int tq = 0; tq < 16; ++tq) {
                const float v0 = fmaxf(yv[2*tq], yv[2*tq+1]);
                const float v1 = fmaxf(yv[2*tq+1], yv[(2*tq+2 < 32) ? 2*tq+2 : 31]);
                op[(size_t)tq*84800] = fmaxf(fmaxf(fmaf(v0,sc,sh), fmaf(v1,sc,sh)), 0.f);
            }
        }
    }
}

// ---------------------------------------------------------------------------
// In-place channel shuffle of d_out rows: group-major (g*200+pq) -> pq*8+g
// ---------------------------------------------------------------------------
__global__ __launch_bounds__(256) void tc_shuffle(float* __restrict__ o) {
    __shared__ float row[1600];
    const size_t base = (size_t)blockIdx.x * 1600;
    const int tid = threadIdx.x;
    #pragma unroll
    for (int it = 0; it < 2; ++it) {
        const int f4 = tid + it*256;
        if (f4 < 400)
            *reinterpret_cast<float4*>(&row[f4*4]) =
                *reinterpret_cast<const float4*>(&o[base + (size_t)f4*4]);
    }
    __syncthreads();
    #pragma unroll
    for (int it = 0; it < 2; ++it) {
        const int f4 = tid + it*256;
        if (f4 < 400) {
            const int c = f4*4;
            float4 v;
            v.x = row[((c  ) & 7)*200 + ((c  ) >> 3)];
            v.y = row[((c+1) & 7)*200 + ((c+1) >> 3)];
            v.z = row[((c+2) & 7)*200 + ((c+2) >> 3)];
            v.w = row[((c+3) & 7)*200 + ((c+3) >> 3)];
            *reinterpret_cast<float4*>(&o[base + (size_t)c]) = v;
        }
    }
}

extern "C" void kernel_launch(void* const* d_in, const int* in_sizes, int n_in,
                              void* d_out, int out_size, void* d_ws, size_t ws_size,
                              hipStream_t stream) {
    const float* x    = (const float*)d_in[0];
    const float* w0   = (const float*)d_in[1];
    const float* b0   = (const float*)d_in[2];
    const float* k3_0 = (const float*)d_in[3];
    const float* k5_0 = (const float*)d_in[4];
    const float* k7_0 = (const float*)d_in[5];
    const float* g0   = (const float*)d_in[6];
    const float* be0  = (const float*)d_in[7];
    const float* mu0  = (const float*)d_in[8];
    const float* v0   = (const float*)d_in[9];
    const float* w1   = (const float*)d_in[10];
    const float* b1   = (const float*)d_in[11];
    const float* k3_1 = (const float*)d_in[12];
    const float* k5_1 = (const float*)d_in[13];
    const float* k7_1 = (const float*)d_in[14];
    const float* g1   = (const float*)d_in[15];
    const float* be1  = (const float*)d_in[16];
    const float* mu1  = (const float*)d_in[17];
    const float* v1   = (const float*)d_in[18];

    // workspace layout (u16 units)
    const size_t n_zb   = 34734080;     // 16*32*53*1280
    const size_t n_W0t  = 163840;       // 8*160*128
    const size_t n_W1t  = 256000;       // 8*200*160
    const size_t n_extb = 2097152;      // 16*2*64*1024
    const size_t n_xb   = 53477376;     // 16*51*64*1024

    unsigned short* zb   = (unsigned short*)d_ws;
    unsigned short* W0t  = zb + n_zb;
    unsigned short* W1t  = W0t + n_W0t;
    unsigned short* extb = W1t + n_W1t;
    unsigned short* xb   = extb + n_extb;
    const size_t need_big = (n_zb + n_W0t + n_W1t + n_extb + n_xb) * 2;
    const int big = (ws_size >= need_big) ? 1 : 0;

    tc_prep   <<<1640, 256, 0, stream>>>(w0, w1, W0t, W1t);
    tc_reduce0<<<16*64, 256, 0, stream>>>(x, xb, extb, big);
    if (big)
        tc_layer0<1><<<816*8, 256, 0, stream>>>(x, xb, extb, W0t, b0, k3_0, k5_0,
                                                k7_0, g0, be0, mu0, v0, zb);
    else
        tc_layer0<0><<<816*8, 256, 0, stream>>>(x, xb, extb, W0t, b0, k3_0, k5_0,
                                                k7_0, g0, be0, mu0, v0, zb);
    tc_reduce1<<<16*32, 320, 0, stream>>>(zb);
    tc_layer1 <<<848*8, 256, 0, stream>>>(zb, W1t, b1, k3_1, k5_1, k7_1,
                                          g1, be1, mu1, v1, (float*)d_out);
    tc_shuffle<<<16*16*53, 256, 0, stream>>>((float*)d_out);
}

// Round 6
// 265.101 us; speedup vs baseline: 6.8265x; 1.0811x over previous
//
#include <hip/hip_runtime.h>
#include <hip/hip_bf16.h>

#define EPSBN 1e-3f

typedef __attribute__((ext_vector_type(8))) short bf16x8;
typedef __attribute__((ext_vector_type(8))) unsigned short ushort8;
typedef __attribute__((ext_vector_type(4))) float f32x4;

// ---------------------------------------------------------------------------
//   x    : (16, 64, 49, 1024) f32
//   xb   : (16, 51, 64, 1024) bf16   [s<49: copy of x; s=49: max; s=50: mean]
//   extb : (16, 2, 64, 1024)  bf16   fallback when ws too small for xb
//   zb2  : (16, 32, 53, 1280) bf16   GROUP-MAJOR ch = g0*160 + (p*32+n);
//                                    s<51 by layer0, s=51,52 by reduce1
//   W0t  : bf16 [8 g][160 n][128 k]
//   W1t  : bf16 [8 g][200 n][160 k-permuted] (kref = (k%20)*8 + k/20)
//   og   : (16, 16, 53, 1600) bf16   group-major layer1 output
//   out  : (16, 16, 53, 1600) f32    ref channel order (pq*8+g), by tc_shuffle
// ---------------------------------------------------------------------------

__device__ __forceinline__ float bf2f(unsigned short u) {
    union { unsigned int i; float f; } c; c.i = (unsigned int)u << 16; return c.f;
}
__device__ __forceinline__ unsigned short f2bf(float f) {
    union { float f; unsigned int i; } c; c.f = f;
    unsigned int r = c.i + 0x7FFF + ((c.i >> 16) & 1);   // RNE
    return (unsigned short)(r >> 16);
}

// ---------------------------------------------------------------------------
__global__ __launch_bounds__(256) void tc_prep(const float* __restrict__ w0,
                                               const float* __restrict__ w1,
                                               unsigned short* __restrict__ W0t,
                                               unsigned short* __restrict__ W1t) {
    const int idx = blockIdx.x * 256 + threadIdx.x;
    if (idx < 163840) {                         // 8*160*128
        const int g   = idx / 20480;
        const int rem = idx - g*20480;
        const int n   = rem >> 7;
        const int k   = rem & 127;
        const int p   = n >> 5, nn = n & 31;
        W0t[idx] = f2bf(w0[(((size_t)p*8 + g)*128 + k)*32 + nn]);
    } else if (idx < 163840 + 256000) {         // 8*200*160
        const int i2  = idx - 163840;
        const int g   = i2 / 32000;
        const int rem = i2 - g*32000;
        const int n   = rem / 160;
        const int k   = rem - n*160;
        const int kref = (k % 20)*8 + k/20;
        const int p   = n / 40, nn = n - p*40;
        W1t[i2] = f2bf(w1[(((size_t)p*8 + g)*160 + kref)*40 + nn]);
    }
}

// ---------------------------------------------------------------------------
__global__ __launch_bounds__(256) void tc_reduce0(const float* __restrict__ x,
                                                  unsigned short* __restrict__ xb,
                                                  unsigned short* __restrict__ extb,
                                                  const int big) {
    const int bt = blockIdx.x;              // b*64+t
    const int b  = bt >> 6, t = bt & 63;
    const int c  = threadIdx.x * 4;
    const float4* src = reinterpret_cast<const float4*>(x + (size_t)bt * 49 * 1024 + c);
    float4 v = src[0];
    float mx0 = v.x, mx1 = v.y, mx2 = v.z, mx3 = v.w;
    float sm0 = v.x, sm1 = v.y, sm2 = v.z, sm3 = v.w;
    if (big) {
        ushort4 o; o.x=f2bf(v.x); o.y=f2bf(v.y); o.z=f2bf(v.z); o.w=f2bf(v.w);
        *reinterpret_cast<ushort4*>(&xb[((size_t)(b*51)*64 + t)*1024 + c]) = o;
    }
    for (int s = 1; s < 49; ++s) {
        float4 u = src[(size_t)s * 256];
        mx0 = fmaxf(mx0, u.x); sm0 += u.x;
        mx1 = fmaxf(mx1, u.y); sm1 += u.y;
        mx2 = fmaxf(mx2, u.z); sm2 += u.z;
        mx3 = fmaxf(mx3, u.w); sm3 += u.w;
        if (big) {
            ushort4 o; o.x=f2bf(u.x); o.y=f2bf(u.y); o.z=f2bf(u.z); o.w=f2bf(u.w);
            *reinterpret_cast<ushort4*>(&xb[((size_t)(b*51 + s)*64 + t)*1024 + c]) = o;
        }
    }
    const float inv = 1.0f / 49.0f;
    ushort4 omx, omn;
    omx.x=f2bf(mx0); omx.y=f2bf(mx1); omx.z=f2bf(mx2); omx.w=f2bf(mx3);
    omn.x=f2bf(sm0*inv); omn.y=f2bf(sm1*inv); omn.z=f2bf(sm2*inv); omn.w=f2bf(sm3*inv);
    if (big) {
        *reinterpret_cast<ushort4*>(&xb[((size_t)(b*51 + 49)*64 + t)*1024 + c]) = omx;
        *reinterpret_cast<ushort4*>(&xb[((size_t)(b*51 + 50)*64 + t)*1024 + c]) = omn;
    } else {
        *reinterpret_cast<ushort4*>(&extb[((size_t)(b*2 + 0)*64 + t)*1024 + c]) = omx;
        *reinterpret_cast<ushort4*>(&extb[((size_t)(b*2 + 1)*64 + t)*1024 + c]) = omn;
    }
}

// ---------------------------------------------------------------------------
// Layer 0: block (b, s<51, g<8).  MFMA D = W^T x A^T -> Yt[n][t] bf16 in LDS,
// Yt row stride 70 u16 (35 dwords, odd) -> conflict-free epilogue reads.
// ---------------------------------------------------------------------------
template<int BIG>
__global__ __launch_bounds__(256, 5) void tc_layer0(
    const float* __restrict__ x, const unsigned short* __restrict__ xb,
    const unsigned short* __restrict__ extb,
    const unsigned short* __restrict__ W0t, const float* __restrict__ bias,
    const float* __restrict__ k3, const float* __restrict__ k5,
    const float* __restrict__ k7,
    const float* __restrict__ gam, const float* __restrict__ bet,
    const float* __restrict__ mu, const float* __restrict__ var,
    unsigned short* __restrict__ zb)
{
    const int tid = threadIdx.x;
    const int g  = blockIdx.x / 816;
    const int bs = blockIdx.x % 816;
    const int s  = bs % 51;
    const int b  = bs / 51;

    __shared__ __align__(16) unsigned short lds[15104];     // 30.2 KB
    unsigned short* AtU = lds;                              // 64 x 136 bf16
    unsigned short* WtU = lds + 64*136;                     // 160 x 40 bf16 (32-k chunk)
    unsigned short* Ytb = lds;                              // 160 x 70 bf16 (overlay, 11200 u16)

    // ---- stage At (64 t x 128 k) bf16 ----
    #pragma unroll
    for (int it = 0; it < 4; ++it) {
        const int fid = tid + it*256;           // < 1024
        const int row = fid >> 4;
        const int ch8 = (fid & 15) * 8;
        ushort8 u;
        if (BIG) {
            u = *reinterpret_cast<const ushort8*>(
                &xb[((size_t)(b*51 + s)*64 + row)*1024 + g*128 + ch8]);
        } else if (s < 49) {
            const float* sp = x + ((size_t)(b*64 + row)*49 + s)*1024 + g*128 + ch8;
            const float4 f0 = *reinterpret_cast<const float4*>(sp);
            const float4 f1 = *reinterpret_cast<const float4*>(sp + 4);
            u[0]=f2bf(f0.x); u[1]=f2bf(f0.y); u[2]=f2bf(f0.z); u[3]=f2bf(f0.w);
            u[4]=f2bf(f1.x); u[5]=f2bf(f1.y); u[6]=f2bf(f1.z); u[7]=f2bf(f1.w);
        } else {
            u = *reinterpret_cast<const ushort8*>(
                &extb[((size_t)(b*2 + (s-49))*64 + row)*1024 + g*128 + ch8]);
        }
        *reinterpret_cast<ushort8*>(&AtU[row*136 + ch8]) = u;
    }

    const int lane = tid & 63;
    const int wid  = tid >> 6;              // t-tile 0..3
    const int fr   = lane & 15;
    const int kb   = lane >> 4;

    f32x4 zero = {0.f, 0.f, 0.f, 0.f};
    f32x4 acc[10];
    #pragma unroll
    for (int i = 0; i < 10; ++i) acc[i] = zero;

    for (int kc = 0; kc < 4; ++kc) {
        __syncthreads();
        #pragma unroll
        for (int it = 0; it < 3; ++it) {        // stage 160 n x 32 k
            const int gi = tid + it*256;        // < 640
            if (gi < 640) {
                const int n = gi >> 2, part = (gi & 3) * 8;
                *reinterpret_cast<ushort8*>(&WtU[n*40 + part]) =
                    *reinterpret_cast<const ushort8*>(
                        &W0t[((size_t)g*160 + n)*128 + kc*32 + part]);
            }
        }
        __syncthreads();
        const bf16x8 bfrag = *reinterpret_cast<const bf16x8*>(
            &AtU[(wid*16 + fr)*136 + kc*32 + kb*8]);
        #pragma unroll
        for (int nt = 0; nt < 10; ++nt) {
            const bf16x8 afrag = *reinterpret_cast<const bf16x8*>(
                &WtU[(nt*16 + fr)*40 + kb*8]);
            acc[nt] = __builtin_amdgcn_mfma_f32_16x16x32_bf16(afrag, bfrag, acc[nt], 0, 0, 0);
        }
    }
    __syncthreads();
    // D: row(n) = nt*16 + kb*4 + r, col(t) = wid*16 + fr
    #pragma unroll
    for (int nt = 0; nt < 10; ++nt)
        #pragma unroll
        for (int r = 0; r < 4; ++r)
            Ytb[(nt*16 + kb*4 + r)*70 + wid*16 + fr] = f2bf(acc[nt][r]);
    __syncthreads();

    // ---- epilogue: one thread per channel ----
    if (tid < 160) {
        const int ch = tid;
        const int p  = ch >> 5, n = ch & 31;
        const int pi = (p*8 + g)*32 + n;
        const float bsv = bias[pi];
        const float sc  = gam[pi]*rsqrtf(var[pi]+EPSBN);
        const float sh  = bet[pi] - mu[pi]*sc;
        float yv[64];
        #pragma unroll
        for (int i = 0; i < 32; ++i) {
            const unsigned int w2 = *reinterpret_cast<const unsigned int*>(&Ytb[ch*70 + i*2]);
            yv[2*i]   = bf2f((unsigned short)(w2 & 0xffffu)) + bsv;
            yv[2*i+1] = bf2f((unsigned short)(w2 >> 16)) + bsv;
        }
        unsigned short* zp = zb + ((size_t)(b*32)*53 + s)*1280 + g*160 + ch;
        if (p == 0) {
            #pragma unroll
            for (int tq = 0; tq < 32; ++tq) {
                const float r = fmaxf(fmaxf(fmaf(yv[2*tq],sc,sh), fmaf(yv[2*tq+1],sc,sh)), 0.f);
                zp[(size_t)tq*67840] = f2bf(r);
            }
        } else if (p == 1) {
            const float w0_ = k3[(g*32+n)*3+0], w1_ = k3[(g*32+n)*3+1], w2_ = k3[(g*32+n)*3+2];
            #pragma unroll
            for (int tq = 0; tq < 32; ++tq) {
                float a = yv[2*tq]*w1_;
                if (tq > 0) a = fmaf(yv[2*tq-1], w0_, a);
                a = fmaf(yv[2*tq+1], w2_, a);
                float c2 = fmaf(yv[2*tq], w0_, yv[2*tq+1]*w1_);
                if (tq < 31) c2 = fmaf(yv[2*tq+2], w2_, c2);
                const float r = fmaxf(fmaxf(fmaf(a,sc,sh), fmaf(c2,sc,sh)), 0.f);
                zp[(size_t)tq*67840] = f2bf(r);
            }
        } else if (p == 2) {
            float wk[5];
            #pragma unroll
            for (int j = 0; j < 5; ++j) wk[j] = k5[(g*32+n)*5+j];
            #pragma unroll
            for (int tq = 0; tq < 32; ++tq) {
                float vv[2];
                #pragma unroll
                for (int q = 0; q < 2; ++q) {
                    const int t = 2*tq + q;
                    float v = 0.f;
                    #pragma unroll
                    for (int j = 0; j < 5; ++j) {
                        const int ttp = t + j - 2;
                        if (ttp >= 0 && ttp < 64) v = fmaf(yv[ttp], wk[j], v);
                    }
                    vv[q] = v;
                }
                const float r = fmaxf(fmaxf(fmaf(vv[0],sc,sh), fmaf(vv[1],sc,sh)), 0.f);
                zp[(size_t)tq*67840] = f2bf(r);
            }
        } else if (p == 3) {
            float wk[7];
            #pragma unroll
            for (int j = 0; j < 7; ++j) wk[j] = k7[(g*32+n)*7+j];
            #pragma unroll
            for (int tq = 0; tq < 32; ++tq) {
                float vv[2];
                #pragma unroll
                for (int q = 0; q < 2; ++q) {
                    const int t = 2*tq + q;
                    float v = 0.f;
                    #pragma unroll
                    for (int j = 0; j < 7; ++j) {
                        const int ttp = t + j - 3;
                        if (ttp >= 0 && ttp < 64) v = fmaf(yv[ttp], wk[j], v);
                    }
                    vv[q] = v;
                }
                const float r = fmaxf(fmaxf(fmaf(vv[0],sc,sh), fmaf(vv[1],sc,sh)), 0.f);
                zp[(size_t)tq*67840] = f2bf(r);
            }
        } else {
            #pragma unroll
            for (int tq = 0; tq < 32; ++tq) {
                const float v0 = fmaxf(yv[2*tq], yv[2*tq+1]);
                const float v1 = fmaxf(yv[2*tq+1], yv[(2*tq+2 < 64) ? 2*tq+2 : 63]);
                const float r = fmaxf(fmaxf(fmaf(v0,sc,sh), fmaf(v1,sc,sh)), 0.f);
                zp[(size_t)tq*67840] = f2bf(r);
            }
        }
    }
}

// ---------------------------------------------------------------------------
// reduce1: fills zb2 columns s=51 (max) and s=52 (mean) per (b,tq) row.
// ---------------------------------------------------------------------------
__global__ __launch_bounds__(320) void tc_reduce1(unsigned short* __restrict__ zb) {
    const int bt = blockIdx.x;              // b*32+tq
    const int c  = threadIdx.x * 4;         // 0..1276
    unsigned short* base = zb + (size_t)bt * 67840;
    ushort4 u = *reinterpret_cast<const ushort4*>(&base[c]);
    float v0 = bf2f(u.x), v1 = bf2f(u.y), v2 = bf2f(u.z), v3 = bf2f(u.w);
    float mx0 = v0, mx1 = v1, mx2 = v2, mx3 = v3;
    float sm0 = v0, sm1 = v1, sm2 = v2, sm3 = v3;
    for (int s = 1; s < 51; ++s) {
        ushort4 w = *reinterpret_cast<const ushort4*>(&base[(size_t)s*1280 + c]);
        v0 = bf2f(w.x); v1 = bf2f(w.y); v2 = bf2f(w.z); v3 = bf2f(w.w);
        mx0 = fmaxf(mx0, v0); sm0 += v0;
        mx1 = fmaxf(mx1, v1); sm1 += v1;
        mx2 = fmaxf(mx2, v2); sm2 += v2;
        mx3 = fmaxf(mx3, v3); sm3 += v3;
    }
    const float inv = 1.0f / 51.0f;
    ushort4 o;
    o.x = f2bf(mx0); o.y = f2bf(mx1); o.z = f2bf(mx2); o.w = f2bf(mx3);
    *reinterpret_cast<ushort4*>(&base[(size_t)51*1280 + c]) = o;
    o.x = f2bf(sm0*inv); o.y = f2bf(sm1*inv); o.z = f2bf(sm2*inv); o.w = f2bf(sm3*inv);
    *reinterpret_cast<ushort4*>(&base[(size_t)52*1280 + c]) = o;
}

// ---------------------------------------------------------------------------
// Layer 1: block (b, s-pair, g).  M = 64 rows = 2 s-columns x 32 t.
// 4 waves, each owns one 16-row t-tile x all 200 n (13 nt, rows 200..207 zero).
// Output og bf16 group-major.
// ---------------------------------------------------------------------------
__global__ __launch_bounds__(256, 4) void tc_layer1(
    const unsigned short* __restrict__ zbi,
    const unsigned short* __restrict__ W1t, const float* __restrict__ bias,
    const float* __restrict__ k3, const float* __restrict__ k5,
    const float* __restrict__ k7,
    const float* __restrict__ gam, const float* __restrict__ bet,
    const float* __restrict__ mu, const float* __restrict__ var,
    unsigned short* __restrict__ og)
{
    const int tid = threadIdx.x;
    const int g   = blockIdx.x / 432;       // 432 = 16 b * 27 s-pairs; 432%8==0
    const int rem = blockIdx.x % 432;
    const int sp  = rem % 27;
    const int b   = rem / 27;
    const int s0  = sp*2;
    const int has1 = (s0 + 1 < 53);

    __shared__ __align__(16) unsigned short lds[64*168 + 208*40];   // 19072 u16 = 38.1 KB
    unsigned short* AtU = lds;              // [64][168] bf16 (rows 0-31: s0, 32-63: s1)
    unsigned short* WtU = lds + 64*168;     // [208][40] bf16 (rows 200-207 zero)
    unsigned short* Ytb = lds;              // [200][70] bf16 overlay (14000 u16)

    // zero W pad rows once (region beyond Ytb overlay, survives)
    if (tid < 40) {
        ushort8 z8 = {0,0,0,0,0,0,0,0};
        const int r = tid / 5, cp = tid - r*5;
        *reinterpret_cast<ushort8*>(&WtU[(200 + r)*40 + cp*8]) = z8;
    }

    // ---- gather At (64 rows x 160 k, z0g k-order) ----
    #pragma unroll
    for (int it = 0; it < 10; ++it) {
        const int fid = tid + it*256;           // < 2560
        const int row = fid / 40;
        const int seg = fid - row*40;
        const int gg  = seg / 5, q = seg - gg*5;
        const int ch  = gg*160 + g*20 + q*4;
        const int s   = (row < 32) ? s0 : (has1 ? s0+1 : s0);
        const int t   = row & 31;
        const unsigned short* src = zbi + ((size_t)(b*32 + t)*53 + s)*1280 + ch;
        *reinterpret_cast<ushort4*>(&AtU[row*168 + seg*4]) =
            *reinterpret_cast<const ushort4*>(src);
    }

    const int lane = tid & 63;
    const int wid  = tid >> 6;              // t-tile 0..3 over M=64
    const int fr   = lane & 15;
    const int kb   = lane >> 4;

    f32x4 zero = {0.f, 0.f, 0.f, 0.f};
    f32x4 acc[13];
    #pragma unroll
    for (int i = 0; i < 13; ++i) acc[i] = zero;

    for (int kc = 0; kc < 5; ++kc) {
        __syncthreads();
        #pragma unroll
        for (int it = 0; it < 4; ++it) {        // stage 200 n x 32 k
            const int gi = tid + it*256;        // < 800
            if (gi < 800) {
                const int n = gi >> 2, part = (gi & 3) * 8;
                *reinterpret_cast<ushort8*>(&WtU[n*40 + part]) =
                    *reinterpret_cast<const ushort8*>(
                        &W1t[((size_t)g*200 + n)*160 + kc*32 + part]);
            }
        }
        __syncthreads();
        const bf16x8 bfrag = *reinterpret_cast<const bf16x8*>(
            &AtU[(wid*16 + fr)*168 + kc*32 + kb*8]);
        #pragma unroll
        for (int nt = 0; nt < 13; ++nt) {
            const bf16x8 afrag = *reinterpret_cast<const bf16x8*>(
                &WtU[(nt*16 + fr)*40 + kb*8]);
            acc[nt] = __builtin_amdgcn_mfma_f32_16x16x32_bf16(afrag, bfrag, acc[nt], 0, 0, 0);
        }
    }
    __syncthreads();
    #pragma unroll
    for (int nt = 0; nt < 13; ++nt) {
        #pragma unroll
        for (int r = 0; r < 4; ++r) {
            const int n = nt*16 + kb*4 + r;
            if (n < 200) Ytb[n*70 + wid*16 + fr] = f2bf(acc[nt][r]);
        }
    }
    __syncthreads();

    // ---- epilogue: 400 tasks = 200 ch x 2 s ----
    #pragma unroll
    for (int it = 0; it < 2; ++it) {
        const int task = tid + it*256;
        if (task < 400) {
            const int sIdx = (task >= 200) ? 1 : 0;
            const int ch   = task - sIdx*200;
            if (sIdx && !has1) continue;
            const int s  = s0 + sIdx;
            const int p  = ch / 40, n = ch - p*40;
            const int pi = (p*8 + g)*40 + n;
            const float bsv = bias[pi];
            const float sc  = gam[pi]*rsqrtf(var[pi]+EPSBN);
            const float sh  = bet[pi] - mu[pi]*sc;
            float yv[32];
            #pragma unroll
            for (int i = 0; i < 16; ++i) {
                const unsigned int w2 = *reinterpret_cast<const unsigned int*>(
                    &Ytb[ch*70 + sIdx*32 + i*2]);
                yv[2*i]   = bf2f((unsigned short)(w2 & 0xffffu)) + bsv;
                yv[2*i+1] = bf2f((unsigned short)(w2 >> 16)) + bsv;
            }
            unsigned short* op = og + ((size_t)(b*16)*53 + s)*1600 + g*200 + ch;
            if (p == 0) {
                #pragma unroll
                for (int tq = 0; tq < 16; ++tq) {
                    const float r = fmaxf(fmaxf(fmaf(yv[2*tq],sc,sh), fmaf(yv[2*tq+1],sc,sh)), 0.f);
                    op[(size_t)tq*84800] = f2bf(r);
                }
            } else if (p == 1) {
                const float w0_ = k3[(g*40+n)*3+0], w1_ = k3[(g*40+n)*3+1], w2_ = k3[(g*40+n)*3+2];
                #pragma unroll
                for (int tq = 0; tq < 16; ++tq) {
                    float a = yv[2*tq]*w1_;
                    if (tq > 0) a = fmaf(yv[2*tq-1], w0_, a);
                    a = fmaf(yv[2*tq+1], w2_, a);
                    float c2 = fmaf(yv[2*tq], w0_, yv[2*tq+1]*w1_);
                    if (tq < 15) c2 = fmaf(yv[2*tq+2], w2_, c2);
                    const float r = fmaxf(fmaxf(fmaf(a,sc,sh), fmaf(c2,sc,sh)), 0.f);
                    op[(size_t)tq*84800] = f2bf(r);
                }
            } else if (p == 2) {
                float wk[5];
                #pragma unroll
                for (int j = 0; j < 5; ++j) wk[j] = k5[(g*40+n)*5+j];
                #pragma unroll
                for (int tq = 0; tq < 16; ++tq) {
                    float vv[2];
                    #pragma unroll
                    for (int q = 0; q < 2; ++q) {
                        const int t = 2*tq + q;
                        float v = 0.f;
                        #pragma unroll
                        for (int j = 0; j < 5; ++j) {
                            const int ttp = t + j - 2;
                            if (ttp >= 0 && ttp < 32) v = fmaf(yv[ttp], wk[j], v);
                        }
                        vv[q] = v;
                    }
                    const float r = fmaxf(fmaxf(fmaf(vv[0],sc,sh), fmaf(vv[1],sc,sh)), 0.f);
                    op[(size_t)tq*84800] = f2bf(r);
                }
            } else if (p == 3) {
                float wk[7];
                #pragma unroll
                for (int j = 0; j < 7; ++j) wk[j] = k7[(g*40+n)*7+j];
                #pragma unroll
                for (int tq = 0; tq < 16; ++tq) {
                    float vv[2];
                    #pragma unroll
                    for (int q = 0; q < 2; ++q) {
                        const int t = 2*tq + q;
                        float v = 0.f;
                        #pragma unroll
                        for (int j = 0; j < 7; ++j) {
                            const int ttp = t + j - 3;
                            if (ttp >= 0 && ttp < 32) v = fmaf(yv[ttp], wk[j], v);
                        }
                        vv[q] = v;
                    }
                    const float r = fmaxf(fmaxf(fmaf(vv[0],sc,sh), fmaf(vv[1],sc,sh)), 0.f);
                    op[(size_t)tq*84800] = f2bf(r);
                }
            } else {
                #pragma unroll
                for (int tq = 0; tq < 16; ++tq) {
                    const float v0 = fmaxf(yv[2*tq], yv[2*tq+1]);
                    const float v1 = fmaxf(yv[2*tq+1], yv[(2*tq+2 < 32) ? 2*tq+2 : 31]);
                    const float r = fmaxf(fmaxf(fmaf(v0,sc,sh), fmaf(v1,sc,sh)), 0.f);
                    op[(size_t)tq*84800] = f2bf(r);
                }
            }
        }
    }
}

// ---------------------------------------------------------------------------
// Shuffle: read og bf16 group-major (g*200+pq) -> write f32 ref order pq*8+g
// ---------------------------------------------------------------------------
__global__ __launch_bounds__(256) void tc_shuffle(const unsigned short* __restrict__ og,
                                                  float* __restrict__ o) {
    __shared__ unsigned short row[1600];
    const size_t base = (size_t)blockIdx.x * 1600;
    const int tid = threadIdx.x;
    if (tid < 200)
        *reinterpret_cast<ushort8*>(&row[tid*8]) =
            *reinterpret_cast<const ushort8*>(&og[base + (size_t)tid*8]);
    __syncthreads();
    #pragma unroll
    for (int it = 0; it < 2; ++it) {
        const int f4 = tid + it*256;
        if (f4 < 400) {
            const int c = f4*4;
            float4 v;
            v.x = bf2f(row[((c  ) & 7)*200 + ((c  ) >> 3)]);
            v.y = bf2f(row[((c+1) & 7)*200 + ((c+1) >> 3)]);
            v.z = bf2f(row[((c+2) & 7)*200 + ((c+2) >> 3)]);
            v.w = bf2f(row[((c+3) & 7)*200 + ((c+3) >> 3)]);
            *reinterpret_cast<float4*>(&o[base + (size_t)c]) = v;
        }
    }
}

extern "C" void kernel_launch(void* const* d_in, const int* in_sizes, int n_in,
                              void* d_out, int out_size, void* d_ws, size_t ws_size,
                              hipStream_t stream) {
    const float* x    = (const float*)d_in[0];
    const float* w0   = (const float*)d_in[1];
    const float* b0   = (const float*)d_in[2];
    const float* k3_0 = (const float*)d_in[3];
    const float* k5_0 = (const float*)d_in[4];
    const float* k7_0 = (const float*)d_in[5];
    const float* g0   = (const float*)d_in[6];
    const float* be0  = (const float*)d_in[7];
    const float* mu0  = (const float*)d_in[8];
    const float* v0   = (const float*)d_in[9];
    const float* w1   = (const float*)d_in[10];
    const float* b1   = (const float*)d_in[11];
    const float* k3_1 = (const float*)d_in[12];
    const float* k5_1 = (const float*)d_in[13];
    const float* k7_1 = (const float*)d_in[14];
    const float* g1   = (const float*)d_in[15];
    const float* be1  = (const float*)d_in[16];
    const float* mu1  = (const float*)d_in[17];
    const float* v1   = (const float*)d_in[18];

    // workspace layout (u16 units)
    const size_t n_zb   = 34734080;     // 16*32*53*1280
    const size_t n_W0t  = 163840;       // 8*160*128
    const size_t n_W1t  = 256000;       // 8*200*160
    const size_t n_extb = 2097152;      // 16*2*64*1024
    const size_t n_og   = 21708800;     // 16*16*53*1600
    const size_t n_xb   = 53477376;     // 16*51*64*1024

    unsigned short* zb   = (unsigned short*)d_ws;
    unsigned short* W0t  = zb + n_zb;
    unsigned short* W1t  = W0t + n_W0t;
    unsigned short* extb = W1t + n_W1t;
    unsigned short* og   = extb + n_extb;
    unsigned short* xb   = og + n_og;
    const size_t need_big = (n_zb + n_W0t + n_W1t + n_extb + n_og + n_xb) * 2;
    const int big = (ws_size >= need_big) ? 1 : 0;

    tc_prep   <<<1640, 256, 0, stream>>>(w0, w1, W0t, W1t);
    tc_reduce0<<<16*64, 256, 0, stream>>>(x, xb, extb, big);
    if (big)
        tc_layer0<1><<<816*8, 256, 0, stream>>>(x, xb, extb, W0t, b0, k3_0, k5_0,
                                                k7_0, g0, be0, mu0, v0, zb);
    else
        tc_layer0<0><<<816*8, 256, 0, stream>>>(x, xb, extb, W0t, b0, k3_0, k5_0,
                                                k7_0, g0, be0, mu0, v0, zb);
    tc_reduce1<<<16*32, 320, 0, stream>>>(zb);
    tc_layer1 <<<432*8, 256, 0, stream>>>(zb, W1t, b1, k3_1, k5_1, k7_1,
                                          g1, be1, mu1, v1, og);
    tc_shuffle<<<16*16*53, 256, 0, stream>>>(og, (float*)d_out);
}